// Round 7
// baseline (535.597 us; speedup 1.0000x reference)
//
#include <hip/hip_runtime.h>
#include <math.h>

// ---------------------------------------------------------------------------
// SelectiveSSM (Mamba block) for MI355X — round 7:
//  * MFMA GEMMs double-buffered (T3/T4 minimum 2-phase: stage-issue before
//    compute, single counted vmcnt(0) AFTER the MFMA cluster, raw s_barrier)
//  * conv+silu fused with xi packing (deletes 67MB packsplit pass)
//
// ws layout (floats) — same 152.7 MB as verified round-0 layout:
//   xz    : 16,777,216   (xi_raw 0..2047 | z 2048..4095)
//   xi    :  8,388,608   (post conv+silu; reused as ygP after pass3)
//   xdbl  :    393,216   (WxTP first, then dt_lin 0..63 | B 64..79 | C 80..95)
//   dtyg  :  8,388,608   (WinTP+xP -> xiP -> dt -> yg)
//   A2    :     32,768
//   cP    :  2,097,152   (xdbl partials span cP+cH; then scan products;
//   cH    :  2,097,152    cP reused as WoutTP after pass2)
// ---------------------------------------------------------------------------

#define D_INNER 2048
#define D_STATE 16
#define SEQLEN  2048
#define NBATCH  2
#define NCHUNK  32
#define CHUNKLEN (SEQLEN / NCHUNK)   // 64

using f32x4 = __attribute__((ext_vector_type(4))) float;
using s16x8 = __attribute__((ext_vector_type(8))) short;

__device__ __forceinline__ float siluf(float x) {
  return x / (1.f + __expf(-x));
}
__device__ __forceinline__ float softplusf(float x) {
  return fmaxf(x, 0.f) + log1pf(__expf(-fabsf(x)));
}

// hi = truncate-to-bf16 (residual exact), lo = RNE-bf16(residual).
__device__ __forceinline__ void split_pair(float f0, float f1,
                                           unsigned& hw, unsigned& lw) {
  unsigned b0 = __float_as_uint(f0), b1 = __float_as_uint(f1);
  hw = (b0 >> 16) | (b1 & 0xFFFF0000u);
  float r0 = f0 - __uint_as_float(b0 & 0xFFFF0000u);
  float r1 = f1 - __uint_as_float(b1 & 0xFFFF0000u);
  unsigned c0 = __float_as_uint(r0); c0 += 0x7FFFu + ((c0 >> 16) & 1u);
  unsigned c1 = __float_as_uint(r1); c1 += 0x7FFFu + ((c1 >> 16) & 1u);
  lw = (c0 >> 16) | (c1 & 0xFFFF0000u);
}

// ---------------------------------------------------------------------------
// packsplit: in[R][K] fp32 row-major -> packed [32hi|32lo] bf16 chunks.
// ---------------------------------------------------------------------------
__global__ __launch_bounds__(256) void packsplit_k(
    const float* __restrict__ in, unsigned* __restrict__ out)
{
  size_t g = (size_t)blockIdx.x * 256 + threadIdx.x;
  float f[32];
#pragma unroll
  for (int q = 0; q < 8; ++q)
    *(float4*)&f[q * 4] = *(const float4*)(in + g * 32 + q * 4);
  unsigned* o = out + g * 32;
#pragma unroll
  for (int j = 0; j < 16; ++j) {
    unsigned hw, lw;
    split_pair(f[2 * j], f[2 * j + 1], hw, lw);
    o[j] = hw; o[16 + j] = lw;
  }
}

// ---------------------------------------------------------------------------
// transpack: in[K][N] fp32 row-major (weights) -> out packed [N][K/32][64].
// ---------------------------------------------------------------------------
__global__ __launch_bounds__(256) void transpack_k(
    const float* __restrict__ in, unsigned* __restrict__ out, int K, int N)
{
  __shared__ float tile[32][257];
  const int tid = threadIdx.x;
  const int nb = blockIdx.x * 256;
  const int kc = blockIdx.y;
#pragma unroll 8
  for (int ky = 0; ky < 32; ++ky)
    tile[ky][tid] = in[(size_t)(kc * 32 + ky) * N + nb + tid];
  __syncthreads();
  unsigned* o = out + ((size_t)(nb + tid) * (K >> 5) + kc) * 32;
#pragma unroll
  for (int j = 0; j < 16; ++j) {
    unsigned hw, lw;
    split_pair(tile[2 * j][tid], tile[2 * j + 1][tid], hw, lw);
    o[j] = hw; o[16 + j] = lw;
  }
}

// ---------------------------------------------------------------------------
// transpack for W_x: in[2048][96] -> packed [128][64][64], rows 96..127 zero.
// ---------------------------------------------------------------------------
__global__ __launch_bounds__(128) void transpack_wx_k(
    const float* __restrict__ Wx, unsigned* __restrict__ out)
{
  const int n = threadIdx.x;     // 0..127
  const int kc = blockIdx.x;     // 0..63
  float f[32];
#pragma unroll
  for (int j = 0; j < 32; ++j)
    f[j] = (n < 96) ? Wx[(size_t)(kc * 32 + j) * 96 + n] : 0.f;
  unsigned* o = out + ((size_t)n * 64 + kc) * 32;
#pragma unroll
  for (int j = 0; j < 16; ++j) {
    unsigned hw, lw;
    split_pair(f[2 * j], f[2 * j + 1], hw, lw);
    o[j] = hw; o[16 + j] = lw;
  }
}

// ---------------------------------------------------------------------------
// Split-bf16 MFMA GEMM, double-buffered 2-phase (T3/T4 minimum recipe):
//   prologue: STAGE(buf0, 0); vmcnt(0); barrier
//   loop:     STAGE(buf^1, t+1); ds_read buf; MFMA;
//             lgkmcnt(0)+vmcnt(0); barrier; swap
// The t+1 loads' latency hides under the MFMA cluster; one barrier/k-step.
// C[M,N] = A[M,K] @ Bt[N,K]^T; operands packed [row][K/32][32hi|32lo] bf16.
// acc += ah*bh + ah*bl + al*bh.
// ---------------------------------------------------------------------------
__global__ __launch_bounds__(256, 2) void mgemm_split(
    const unsigned short* __restrict__ A, const unsigned short* __restrict__ Bt,
    float* __restrict__ C, int M, int N, int K, int ldc)
{
  __shared__ s16x8 AsV[2][128 * 8];   // 2 x 16 KB
  __shared__ s16x8 BsV[2][128 * 8];   // 2 x 16 KB

  const int tid = threadIdx.x;
  const int wv  = tid >> 6;
  const int ln  = tid & 63;
  const int wr  = wv >> 1, wc = wv & 1;
  const int m0  = blockIdx.y * 128, n0 = blockIdx.x * 128;
  const int K32 = K >> 5;

  const int rr = ln & 15;
  const int ko = ln >> 4;
  const int sh = ko ^ (rr & 7);
  const int sl = (4 | ko) ^ (rr & 7);
  const int srow  = ln >> 3;
  const int sslot = (ln & 7) ^ srow;

  auto stage = [&](int buf, int ktc) {
#pragma unroll
    for (int t = 0; t < 4; ++t) {
      int i = wv * 4 + t;
      const unsigned short* ga =
          A + ((size_t)(m0 + i * 8 + srow) * K32 + ktc) * 64 + sslot * 8;
      const unsigned short* gb =
          Bt + ((size_t)(n0 + i * 8 + srow) * K32 + ktc) * 64 + sslot * 8;
      __builtin_amdgcn_global_load_lds(
          (const __attribute__((address_space(1))) void*)ga,
          (__attribute__((address_space(3))) void*)((char*)&AsV[buf][0] + i * 1024), 16, 0, 0);
      __builtin_amdgcn_global_load_lds(
          (const __attribute__((address_space(1))) void*)gb,
          (__attribute__((address_space(3))) void*)((char*)&BsV[buf][0] + i * 1024), 16, 0, 0);
    }
  };

  f32x4 acc[4][4];
#pragma unroll
  for (int i = 0; i < 4; i++)
#pragma unroll
    for (int j = 0; j < 4; j++) acc[i][j] = (f32x4)0.f;

  // prologue
  stage(0, 0);
  asm volatile("s_waitcnt vmcnt(0)" ::: "memory");
  __builtin_amdgcn_s_barrier();

  int cur = 0;
  for (int ktc = 0; ktc < K32; ++ktc) {
    if (ktc + 1 < K32) stage(cur ^ 1, ktc + 1);   // issue next tile early

    s16x8 ah[4], al[4], bh[4], bl[4];
#pragma unroll
    for (int mi = 0; mi < 4; ++mi) {
      int r = wr * 64 + mi * 16 + rr;
      ah[mi] = AsV[cur][r * 8 + sh];
      al[mi] = AsV[cur][r * 8 + sl];
    }
#pragma unroll
    for (int ni = 0; ni < 4; ++ni) {
      int c = wc * 64 + ni * 16 + rr;
      bh[ni] = BsV[cur][c * 8 + sh];
      bl[ni] = BsV[cur][c * 8 + sl];
    }
#pragma unroll
    for (int mi = 0; mi < 4; ++mi)
#pragma unroll
      for (int ni = 0; ni < 4; ++ni) {
        acc[mi][ni] = __builtin_amdgcn_mfma_f32_16x16x32_bf16(ah[mi], bh[ni], acc[mi][ni], 0, 0, 0);
        acc[mi][ni] = __builtin_amdgcn_mfma_f32_16x16x32_bf16(ah[mi], bl[ni], acc[mi][ni], 0, 0, 0);
        acc[mi][ni] = __builtin_amdgcn_mfma_f32_16x16x32_bf16(al[mi], bh[ni], acc[mi][ni], 0, 0, 0);
      }

    // reads of buf[cur] done (lgkm) + next tile landed (vm), then converge
    asm volatile("s_waitcnt lgkmcnt(0) vmcnt(0)" ::: "memory");
    __builtin_amdgcn_s_barrier();
    cur ^= 1;
  }

  const int orow = (ln >> 4) * 4;
#pragma unroll
  for (int mi = 0; mi < 4; ++mi)
#pragma unroll
    for (int ni = 0; ni < 4; ++ni) {
      int rowg = m0 + wr * 64 + mi * 16 + orow;
      int colg = n0 + wc * 64 + ni * 16 + rr;
#pragma unroll
      for (int i = 0; i < 4; ++i)
        C[(size_t)(rowg + i) * ldc + colg] = acc[mi][ni][i];
    }
}

// ---------------------------------------------------------------------------
// xdbl split-K MFMA (double-buffered, same 2-phase): P[kz][4096][96] partials.
// ---------------------------------------------------------------------------
__global__ __launch_bounds__(256, 2) void xdbl_mfma_k(
    const unsigned short* __restrict__ A, const unsigned short* __restrict__ Bt,
    float* __restrict__ P)
{
  __shared__ s16x8 AsV[2][128 * 8];
  __shared__ s16x8 BsV[2][128 * 8];

  const int tid = threadIdx.x;
  const int wv  = tid >> 6;
  const int ln  = tid & 63;
  const int wr  = wv >> 1, wc = wv & 1;
  const int kz  = blockIdx.x;            // 0..7
  const int m0  = blockIdx.y * 128;
  const int K32 = 64;                    // K=2048

  const int rr = ln & 15;
  const int ko = ln >> 4;
  const int sh = ko ^ (rr & 7);
  const int sl = (4 | ko) ^ (rr & 7);
  const int srow  = ln >> 3;
  const int sslot = (ln & 7) ^ srow;

  auto stage = [&](int buf, int ktc) {
#pragma unroll
    for (int t = 0; t < 4; ++t) {
      int i = wv * 4 + t;
      const unsigned short* ga =
          A + ((size_t)(m0 + i * 8 + srow) * K32 + ktc) * 64 + sslot * 8;
      const unsigned short* gb =
          Bt + ((size_t)(i * 8 + srow) * K32 + ktc) * 64 + sslot * 8;
      __builtin_amdgcn_global_load_lds(
          (const __attribute__((address_space(1))) void*)ga,
          (__attribute__((address_space(3))) void*)((char*)&AsV[buf][0] + i * 1024), 16, 0, 0);
      __builtin_amdgcn_global_load_lds(
          (const __attribute__((address_space(1))) void*)gb,
          (__attribute__((address_space(3))) void*)((char*)&BsV[buf][0] + i * 1024), 16, 0, 0);
    }
  };

  f32x4 acc[4][4];
#pragma unroll
  for (int i = 0; i < 4; i++)
#pragma unroll
    for (int j = 0; j < 4; j++) acc[i][j] = (f32x4)0.f;

  const int kbeg = kz * 8, kend = kz * 8 + 8;
  stage(0, kbeg);
  asm volatile("s_waitcnt vmcnt(0)" ::: "memory");
  __builtin_amdgcn_s_barrier();

  int cur = 0;
  for (int ktc = kbeg; ktc < kend; ++ktc) {
    if (ktc + 1 < kend) stage(cur ^ 1, ktc + 1);

    s16x8 ah[4], al[4], bh[4], bl[4];
#pragma unroll
    for (int mi = 0; mi < 4; ++mi) {
      int r = wr * 64 + mi * 16 + rr;
      ah[mi] = AsV[cur][r * 8 + sh];
      al[mi] = AsV[cur][r * 8 + sl];
    }
#pragma unroll
    for (int ni = 0; ni < 4; ++ni) {
      int c = wc * 64 + ni * 16 + rr;
      bh[ni] = BsV[cur][c * 8 + sh];
      bl[ni] = BsV[cur][c * 8 + sl];
    }
#pragma unroll
    for (int mi = 0; mi < 4; ++mi)
#pragma unroll
      for (int ni = 0; ni < 4; ++ni) {
        acc[mi][ni] = __builtin_amdgcn_mfma_f32_16x16x32_bf16(ah[mi], bh[ni], acc[mi][ni], 0, 0, 0);
        acc[mi][ni] = __builtin_amdgcn_mfma_f32_16x16x32_bf16(ah[mi], bl[ni], acc[mi][ni], 0, 0, 0);
        acc[mi][ni] = __builtin_amdgcn_mfma_f32_16x16x32_bf16(al[mi], bh[ni], acc[mi][ni], 0, 0, 0);
      }

    asm volatile("s_waitcnt lgkmcnt(0) vmcnt(0)" ::: "memory");
    __builtin_amdgcn_s_barrier();
    cur ^= 1;
  }

  const int orow = (ln >> 4) * 4;
#pragma unroll
  for (int mi = 0; mi < 4; ++mi)
#pragma unroll
    for (int ni = 0; ni < 4; ++ni) {
      int rowg = m0 + wr * 64 + mi * 16 + orow;
      int colg = wc * 64 + ni * 16 + rr;
      if (colg < 96) {
#pragma unroll
        for (int i = 0; i < 4; ++i)
          P[((size_t)kz * 4096 + rowg + i) * 96 + colg] = acc[mi][ni][i];
      }
    }
}

// xdbl[i] = sum over 8 partial slices
__global__ __launch_bounds__(256) void xdbl_reduce_k(
    const float* __restrict__ P, float* __restrict__ xdbl)
{
  int i = blockIdx.x * 256 + threadIdx.x;   // 0..393215
  float s = 0.f;
#pragma unroll
  for (int kz = 0; kz < 8; ++kz) s += P[(size_t)kz * 393216 + i];
  xdbl[i] = s;
}

// ---------------------------------------------------------------------------
// fp32 GEMM (small K=64 dt projection), EPI==1: softplus(acc + bias[col]).
// ---------------------------------------------------------------------------
template <int EPI>
__global__ __launch_bounds__(256, 2) void sgemm_k(
    const float* __restrict__ A, const float* __restrict__ B,
    const float* __restrict__ bias, float* __restrict__ C,
    int M, int N, int K, int lda, int ldb, int ldc)
{
  __shared__ float As[16][132];
  __shared__ float Bs[16][128];

  const int tid = threadIdx.x;
  const int m0 = blockIdx.y * 128;
  const int n0 = blockIdx.x * 128;
  const int tx = tid & 15;
  const int ty = tid >> 4;

  float acc[2][2][4][4];
#pragma unroll
  for (int a = 0; a < 2; a++)
#pragma unroll
    for (int b2 = 0; b2 < 2; b2++)
#pragma unroll
      for (int i = 0; i < 4; i++)
#pragma unroll
        for (int j = 0; j < 4; j++) acc[a][b2][i][j] = 0.f;

  for (int k0 = 0; k0 < K; k0 += 16) {
#pragma unroll
    for (int t = 0; t < 2; ++t) {
      int i = tid + t * 256;
      int row = i >> 2;
      int kq = (i & 3) * 4;
      float4 v = *(const float4*)(A + (size_t)(m0 + row) * lda + k0 + kq);
      As[kq + 0][row] = v.x; As[kq + 1][row] = v.y;
      As[kq + 2][row] = v.z; As[kq + 3][row] = v.w;
    }
#pragma unroll
    for (int t = 0; t < 2; ++t) {
      int i = tid + t * 256;
      int kr = i >> 5;
      int cq = (i & 31) * 4;
      *(float4*)&Bs[kr][cq] = *(const float4*)(B + (size_t)(k0 + kr) * ldb + n0 + cq);
    }
    __syncthreads();
#pragma unroll
    for (int kk = 0; kk < 16; ++kk) {
      float4 a0 = *(const float4*)&As[kk][ty * 4];
      float4 a1 = *(const float4*)&As[kk][64 + ty * 4];
      float4 b0 = *(const float4*)&Bs[kk][tx * 4];
      float4 b1 = *(const float4*)&Bs[kk][64 + tx * 4];
      float av[2][4] = {{a0.x, a0.y, a0.z, a0.w}, {a1.x, a1.y, a1.z, a1.w}};
      float bv[2][4] = {{b0.x, b0.y, b0.z, b0.w}, {b1.x, b1.y, b1.z, b1.w}};
#pragma unroll
      for (int a = 0; a < 2; a++)
#pragma unroll
        for (int i = 0; i < 4; i++)
#pragma unroll
          for (int b2 = 0; b2 < 2; b2++)
#pragma unroll
            for (int j = 0; j < 4; j++)
              acc[a][b2][i][j] = fmaf(av[a][i], bv[b2][j], acc[a][b2][i][j]);
    }
    __syncthreads();
  }

#pragma unroll
  for (int a = 0; a < 2; a++) {
#pragma unroll
    for (int i = 0; i < 4; i++) {
      int row = m0 + a * 64 + ty * 4 + i;
#pragma unroll
      for (int b2 = 0; b2 < 2; b2++) {
        int col = n0 + b2 * 64 + tx * 4;
        float4 v = make_float4(acc[a][b2][i][0], acc[a][b2][i][1],
                               acc[a][b2][i][2], acc[a][b2][i][3]);
        if (EPI == 1) {
          v.x = softplusf(v.x + bias[col + 0]);
          v.y = softplusf(v.y + bias[col + 1]);
          v.z = softplusf(v.z + bias[col + 2]);
          v.w = softplusf(v.w + bias[col + 3]);
        }
        *(float4*)(C + (size_t)row * ldc + col) = v;
      }
    }
  }
}

// ---------------------------------------------------------------------------
// depthwise causal conv1d (taps=4) + bias + silu, FUSED with hi/lo packing.
// Thread = (row, 32-d chunk): writes xi fp32 (8 float4) AND the packed
// 128B chunk of xiP.  grid = 4096*64/256 = 1024 blocks.
// ---------------------------------------------------------------------------
__global__ __launch_bounds__(256) void conv_silu_pack_k(
    const float* __restrict__ xz, const float* __restrict__ cw,
    const float* __restrict__ cb, float* __restrict__ xi,
    unsigned* __restrict__ xiP)
{
  int g = blockIdx.x * 256 + threadIdx.x;   // chunk id = row*64 + ck
  int ck = g & 63;
  int row = g >> 6;
  int l = row & (SEQLEN - 1);
  int d0 = ck * 32;

  float* xo = xi + (size_t)row * D_INNER + d0;
  unsigned* po = xiP + (size_t)g * 32;

#pragma unroll
  for (int q = 0; q < 4; ++q) {             // d-subrange d0+8q .. +8
    int dq = d0 + q * 8;
    float acc[8];
    float4 wv4[8];
#pragma unroll
    for (int e = 0; e < 8; ++e) {
      wv4[e] = *(const float4*)(cw + (size_t)(dq + e) * 4);
      acc[e] = cb[dq + e];
    }
#pragma unroll
    for (int j = 0; j < 4; ++j) {
      int ll = l - 3 + j;
      if (ll >= 0) {
        const float* src = xz + (size_t)(row - 3 + j) * 4096 + dq;
        float4 v0 = *(const float4*)(src);
        float4 v1 = *(const float4*)(src + 4);
        float in[8] = {v0.x, v0.y, v0.z, v0.w, v1.x, v1.y, v1.z, v1.w};
#pragma unroll
        for (int e = 0; e < 8; ++e) {
          float w = (j == 0) ? wv4[e].x : (j == 1) ? wv4[e].y
                   : (j == 2) ? wv4[e].z : wv4[e].w;
          acc[e] = fmaf(w, in[e], acc[e]);
        }
      }
    }
#pragma unroll
    for (int e = 0; e < 8; ++e) acc[e] = siluf(acc[e]);
    *(float4*)(xo + q * 8)     = make_float4(acc[0], acc[1], acc[2], acc[3]);
    *(float4*)(xo + q * 8 + 4) = make_float4(acc[4], acc[5], acc[6], acc[7]);
#pragma unroll
    for (int p = 0; p < 4; ++p) {
      unsigned hw, lw;
      split_pair(acc[2 * p], acc[2 * p + 1], hw, lw);
      po[q * 4 + p] = hw;
      po[16 + q * 4 + p] = lw;
    }
  }
}

__global__ __launch_bounds__(256) void aprep_k(const float* __restrict__ A_log,
                                               float* __restrict__ A2)
{
  int i = blockIdx.x * 256 + threadIdx.x;
  A2[i] = -__expf(A_log[i]);
}

// ---------------------------------------------------------------------------
// chunked selective scan (3 passes) — unchanged
// ---------------------------------------------------------------------------
__global__ __launch_bounds__(256) void scan_pass1(
    const float* __restrict__ dt, const float* __restrict__ xi,
    const float* __restrict__ xdbl, const float* __restrict__ A2,
    float* __restrict__ cP, float* __restrict__ cH)
{
  int d = blockIdx.x * 256 + threadIdx.x;
  int c = blockIdx.y;
  int b = blockIdx.z;
  float a2[D_STATE], h[D_STATE], P[D_STATE];
#pragma unroll
  for (int n = 0; n < D_STATE; n++) {
    a2[n] = A2[d * D_STATE + n];
    h[n] = 0.f;
    P[n] = 1.f;
  }
  int rowbase = b * SEQLEN + c * CHUNKLEN;
  for (int l = 0; l < CHUNKLEN; l++) {
    int row = rowbase + l;
    float dtv = dt[(size_t)row * D_INNER + d];
    float xv = xi[(size_t)row * D_INNER + d];
    float dtx = dtv * xv;
    const float* Bp = xdbl + (size_t)row * 96 + 64;
#pragma unroll
    for (int n = 0; n < D_STATE; n++) {
      float dA = __expf(dtv * a2[n]);
      P[n] *= dA;
      h[n] = fmaf(dA, h[n], dtx * Bp[n]);
    }
  }
  size_t base = ((size_t)(b * D_INNER + d) * NCHUNK + c) * D_STATE;
#pragma unroll
  for (int n = 0; n < D_STATE; n++) {
    cP[base + n] = P[n];
    cH[base + n] = h[n];
  }
}

__global__ __launch_bounds__(256) void scan_pass2(
    const float* __restrict__ cP, float* __restrict__ cH)
{
  int t = blockIdx.x * 256 + threadIdx.x;
  size_t base = (size_t)(t >> 4) * (NCHUNK * D_STATE) + (t & 15);
  float h = 0.f;
  for (int c = 0; c < NCHUNK; c++) {
    size_t idx = base + (size_t)c * D_STATE;
    float Pv = cP[idx];
    float q = cH[idx];
    cH[idx] = h;
    h = fmaf(Pv, h, q);
  }
}

__global__ __launch_bounds__(256) void scan_pass3(
    float* __restrict__ dtyg, const float* __restrict__ xi,
    const float* __restrict__ xdbl, const float* __restrict__ A2,
    const float* __restrict__ cH, const float* __restrict__ Dvec,
    const float* __restrict__ xz)
{
  int d = blockIdx.x * 256 + threadIdx.x;
  int c = blockIdx.y;
  int b = blockIdx.z;
  float a2[D_STATE], h[D_STATE];
  size_t base = ((size_t)(b * D_INNER + d) * NCHUNK + c) * D_STATE;
#pragma unroll
  for (int n = 0; n < D_STATE; n++) {
    a2[n] = A2[d * D_STATE + n];
    h[n] = cH[base + n];
  }
  float Dd = Dvec[d];
  int rowbase = b * SEQLEN + c * CHUNKLEN;
  for (int l = 0; l < CHUNKLEN; l++) {
    int row = rowbase + l;
    float dtv = dtyg[(size_t)row * D_INNER + d];
    float xv = xi[(size_t)row * D_INNER + d];
    float dtx = dtv * xv;
    const float* Bp = xdbl + (size_t)row * 96 + 64;
    const float* Cp = Bp + D_STATE;
    float y = Dd * xv;
#pragma unroll
    for (int n = 0; n < D_STATE; n++) {
      float dA = __expf(dtv * a2[n]);
      h[n] = fmaf(dA, h[n], dtx * Bp[n]);
      y = fmaf(h[n], Cp[n], y);
    }
    float z = xz[(size_t)row * 4096 + D_INNER + d];
    dtyg[(size_t)row * D_INNER + d] = y * siluf(z);
  }
}

// ---------------------------------------------------------------------------
extern "C" void kernel_launch(void* const* d_in, const int* in_sizes, int n_in,
                              void* d_out, int out_size, void* d_ws,
                              size_t ws_size, hipStream_t stream)
{
  const float* x     = (const float*)d_in[0];
  const float* W_in  = (const float*)d_in[1];
  const float* cw    = (const float*)d_in[2];
  const float* cb    = (const float*)d_in[3];
  const float* W_x   = (const float*)d_in[4];
  const float* W_dt  = (const float*)d_in[5];
  const float* b_dt  = (const float*)d_in[6];
  const float* A_log = (const float*)d_in[7];
  const float* Dv    = (const float*)d_in[8];
  const float* W_out = (const float*)d_in[9];
  float* out = (float*)d_out;

  float* ws    = (float*)d_ws;
  float* xz    = ws;                       // 16,777,216
  float* xi    = xz + 16777216;            //  8,388,608
  float* xdbl  = xi + 8388608;             //    393,216
  float* dtyg  = xdbl + 393216;            //  8,388,608
  float* A2    = dtyg + 8388608;           //     32,768
  float* cP    = A2 + 32768;               //  2,097,152
  float* cH    = cP + 2097152;             //  2,097,152

  // packed hi/lo bf16 + partial overlays
  unsigned* WinTP  = (unsigned*)dtyg;                 // GEMM1 B (dead after)
  unsigned* xP     = (unsigned*)(dtyg + 4194304);     // GEMM1 A (dead after)
  unsigned* xiP    = (unsigned*)dtyg;                 // xdbl-GEMM A (dead after)
  unsigned* WxTP   = (unsigned*)xdbl;                 // xdbl-GEMM B (dead before reduce)
  float*    Ppart  = cP;                              // [8][4096][96] spans cP+cH
  unsigned* ygP    = (unsigned*)xi;                   // GEMM2 A (xi dead post-scan)
  unsigned* WoutTP = (unsigned*)cP;                   // GEMM2 B (cP dead post-pass2)

  aprep_k<<<128, 256, 0, stream>>>(A_log, A2);

  // W_in (1024x4096) -> transposed+packed WinTP; x -> packed xP
  transpack_k<<<dim3(16, 32), 256, 0, stream>>>(W_in, WinTP, 1024, 4096);
  packsplit_k<<<512, 256, 0, stream>>>(x, xP);

  // xz = x @ W_in   (4096x4096, K=1024)
  mgemm_split<<<dim3(32, 32), 256, 0, stream>>>(
      (const unsigned short*)xP, (const unsigned short*)WinTP, xz,
      4096, 4096, 1024, 4096);

  // conv + silu + pack (writes xi fp32 AND xiP packed)
  conv_silu_pack_k<<<1024, 256, 0, stream>>>(xz, cw, cb, xi, xiP);

  // x_dbl = xi @ W_x via packed split-bf16 MFMA, split-K=8, private partials
  transpack_wx_k<<<64, 128, 0, stream>>>(W_x, WxTP);
  xdbl_mfma_k<<<dim3(8, 32), 256, 0, stream>>>(
      (const unsigned short*)xiP, (const unsigned short*)WxTP, Ppart);
  xdbl_reduce_k<<<1536, 256, 0, stream>>>(Ppart, xdbl);

  // dt = softplus(x_dbl[:, :64] @ W_dt + b_dt)  (K=64, fp32)
  sgemm_k<1><<<dim3(16, 32), 256, 0, stream>>>(xdbl, W_dt, b_dt, dtyg,
                                               4096, 2048, 64, 96, 2048, 2048);

  scan_pass1<<<dim3(8, NCHUNK, NBATCH), 256, 0, stream>>>(dtyg, xi, xdbl, A2, cP, cH);
  scan_pass2<<<256, 256, 0, stream>>>(cP, cH);
  scan_pass3<<<dim3(8, NCHUNK, NBATCH), 256, 0, stream>>>(dtyg, xi, xdbl, A2, cH, Dv, xz);

  // yg -> packed; W_out -> transposed+packed
  packsplit_k<<<1024, 256, 0, stream>>>(dtyg, ygP);
  transpack_k<<<dim3(4, 64), 256, 0, stream>>>(W_out, WoutTP, 2048, 1024);

  // out = yg @ W_out  (4096x1024, K=2048)
  mgemm_split<<<dim3(8, 32), 256, 0, stream>>>(
      (const unsigned short*)ygP, (const unsigned short*)WoutTP, out,
      4096, 1024, 2048, 1024);
}

// Round 9
// 511.519 us; speedup vs baseline: 1.0471x; 1.0471x over previous
//
#include <hip/hip_runtime.h>
#include <math.h>

// ---------------------------------------------------------------------------
// SelectiveSSM (Mamba block) for MI355X — round 8 (resubmit): round-6
// structure (known 479 µs) + ONE change: GEMM K-loop uses a counted-vmcnt
// 2-deep pipeline (T4: never drain vmcnt(0) in the main loop; wait vmcnt(8)
// = current tile landed while next tile's 8 loads stay in flight).
//
// ws layout (floats) — same 152.7 MB as verified round-0 layout:
//   xz    : 16,777,216   (xi_raw 0..2047 | z 2048..4095)
//   xi    :  8,388,608   (post conv+silu; reused as ygP after pass3)
//   xdbl  :    393,216   (WxTP first, then dt_lin | B | C)
//   dtyg  :  8,388,608   (WinTP+xP -> xiP -> dt -> yg)
//   A2    :     32,768
//   cP    :  2,097,152   (xdbl partials span cP+cH; then scan products;
//   cH    :  2,097,152    cP reused as WoutTP after pass2)
// ---------------------------------------------------------------------------

#define D_INNER 2048
#define D_STATE 16
#define SEQLEN  2048
#define NBATCH  2
#define NCHUNK  32
#define CHUNKLEN (SEQLEN / NCHUNK)   // 64

using f32x4 = __attribute__((ext_vector_type(4))) float;
using s16x8 = __attribute__((ext_vector_type(8))) short;

__device__ __forceinline__ float siluf(float x) {
  return x / (1.f + __expf(-x));
}
__device__ __forceinline__ float softplusf(float x) {
  return fmaxf(x, 0.f) + log1pf(__expf(-fabsf(x)));
}

// hi = truncate-to-bf16 (residual exact), lo = RNE-bf16(residual).
__device__ __forceinline__ void split_pair(float f0, float f1,
                                           unsigned& hw, unsigned& lw) {
  unsigned b0 = __float_as_uint(f0), b1 = __float_as_uint(f1);
  hw = (b0 >> 16) | (b1 & 0xFFFF0000u);
  float r0 = f0 - __uint_as_float(b0 & 0xFFFF0000u);
  float r1 = f1 - __uint_as_float(b1 & 0xFFFF0000u);
  unsigned c0 = __float_as_uint(r0); c0 += 0x7FFFu + ((c0 >> 16) & 1u);
  unsigned c1 = __float_as_uint(r1); c1 += 0x7FFFu + ((c1 >> 16) & 1u);
  lw = (c0 >> 16) | (c1 & 0xFFFF0000u);
}

// ---------------------------------------------------------------------------
// packsplit: in[R][K] fp32 row-major -> packed [32hi|32lo] bf16 chunks.
// ---------------------------------------------------------------------------
__global__ __launch_bounds__(256) void packsplit_k(
    const float* __restrict__ in, unsigned* __restrict__ out)
{
  size_t g = (size_t)blockIdx.x * 256 + threadIdx.x;
  float f[32];
#pragma unroll
  for (int q = 0; q < 8; ++q)
    *(float4*)&f[q * 4] = *(const float4*)(in + g * 32 + q * 4);
  unsigned* o = out + g * 32;
#pragma unroll
  for (int j = 0; j < 16; ++j) {
    unsigned hw, lw;
    split_pair(f[2 * j], f[2 * j + 1], hw, lw);
    o[j] = hw; o[16 + j] = lw;
  }
}

// ---------------------------------------------------------------------------
// transpack: in[K][N] fp32 row-major (weights) -> out packed [N][K/32][64].
// ---------------------------------------------------------------------------
__global__ __launch_bounds__(256) void transpack_k(
    const float* __restrict__ in, unsigned* __restrict__ out, int K, int N)
{
  __shared__ float tile[32][257];
  const int tid = threadIdx.x;
  const int nb = blockIdx.x * 256;
  const int kc = blockIdx.y;
#pragma unroll 8
  for (int ky = 0; ky < 32; ++ky)
    tile[ky][tid] = in[(size_t)(kc * 32 + ky) * N + nb + tid];
  __syncthreads();
  unsigned* o = out + ((size_t)(nb + tid) * (K >> 5) + kc) * 32;
#pragma unroll
  for (int j = 0; j < 16; ++j) {
    unsigned hw, lw;
    split_pair(tile[2 * j][tid], tile[2 * j + 1][tid], hw, lw);
    o[j] = hw; o[16 + j] = lw;
  }
}

// ---------------------------------------------------------------------------
// transpack for W_x: in[2048][96] -> packed [128][64][64], rows 96..127 zero.
// ---------------------------------------------------------------------------
__global__ __launch_bounds__(128) void transpack_wx_k(
    const float* __restrict__ Wx, unsigned* __restrict__ out)
{
  const int n = threadIdx.x;     // 0..127
  const int kc = blockIdx.x;     // 0..63
  float f[32];
#pragma unroll
  for (int j = 0; j < 32; ++j)
    f[j] = (n < 96) ? Wx[(size_t)(kc * 32 + j) * 96 + n] : 0.f;
  unsigned* o = out + ((size_t)n * 64 + kc) * 32;
#pragma unroll
  for (int j = 0; j < 16; ++j) {
    unsigned hw, lw;
    split_pair(f[2 * j], f[2 * j + 1], hw, lw);
    o[j] = hw; o[16 + j] = lw;
  }
}

// ---------------------------------------------------------------------------
// Split-bf16 MFMA GEMM, counted-vmcnt 2-deep pipeline:
//   prologue: stage(buf0,t0); stage(buf1,t0+1)          // 16 loads in flight
//   iter t:   wait vmcnt(8)  (last iter: vmcnt(0))      // tile t landed,
//             s_barrier                                 //   t+1 in flight
//             ds_read buf[t&1] + 48 MFMA
//             s_barrier                                 // buf consumed
//             stage(buf[t&1], t+2) if exists            // refill
// Per-wave wait + barrier = collective "all 32 loads landed" guarantee.
// C[M,N] = A[M,K] @ Bt[N,K]^T; operands packed [row][K/32][32hi|32lo] bf16.
// acc += ah*bh + ah*bl + al*bh.
// ---------------------------------------------------------------------------
__global__ __launch_bounds__(256, 2) void mgemm_split(
    const unsigned short* __restrict__ A, const unsigned short* __restrict__ Bt,
    float* __restrict__ C, int M, int N, int K, int ldc)
{
  __shared__ s16x8 AsV[2][128 * 8];   // 2 x 16 KB
  __shared__ s16x8 BsV[2][128 * 8];   // 2 x 16 KB

  const int tid = threadIdx.x;
  const int wv  = tid >> 6;
  const int ln  = tid & 63;
  const int wr  = wv >> 1, wc = wv & 1;
  const int m0  = blockIdx.y * 128, n0 = blockIdx.x * 128;
  const int K32 = K >> 5;

  const int rr = ln & 15;
  const int ko = ln >> 4;
  const int sh = ko ^ (rr & 7);
  const int sl = (4 | ko) ^ (rr & 7);
  const int srow  = ln >> 3;
  const int sslot = (ln & 7) ^ srow;

  auto stage = [&](int buf, int ktc) {
#pragma unroll
    for (int t = 0; t < 4; ++t) {
      int i = wv * 4 + t;
      const unsigned short* ga =
          A + ((size_t)(m0 + i * 8 + srow) * K32 + ktc) * 64 + sslot * 8;
      const unsigned short* gb =
          Bt + ((size_t)(n0 + i * 8 + srow) * K32 + ktc) * 64 + sslot * 8;
      __builtin_amdgcn_global_load_lds(
          (const __attribute__((address_space(1))) void*)ga,
          (__attribute__((address_space(3))) void*)((char*)&AsV[buf][0] + i * 1024), 16, 0, 0);
      __builtin_amdgcn_global_load_lds(
          (const __attribute__((address_space(1))) void*)gb,
          (__attribute__((address_space(3))) void*)((char*)&BsV[buf][0] + i * 1024), 16, 0, 0);
    }
  };

  f32x4 acc[4][4];
#pragma unroll
  for (int i = 0; i < 4; i++)
#pragma unroll
    for (int j = 0; j < 4; j++) acc[i][j] = (f32x4)0.f;

  stage(0, 0);
  stage(1, 1);           // K32 >= 2 for all call sites (8/32/64)

  int cur = 0;
  for (int ktc = 0; ktc < K32; ++ktc) {
    if (ktc + 1 < K32)
      asm volatile("s_waitcnt vmcnt(8)" ::: "memory");   // tile ktc landed
    else
      asm volatile("s_waitcnt vmcnt(0)" ::: "memory");   // last tile
    __builtin_amdgcn_s_barrier();

    s16x8 ah[4], al[4], bh[4], bl[4];
#pragma unroll
    for (int mi = 0; mi < 4; ++mi) {
      int r = wr * 64 + mi * 16 + rr;
      ah[mi] = AsV[cur][r * 8 + sh];
      al[mi] = AsV[cur][r * 8 + sl];
    }
#pragma unroll
    for (int ni = 0; ni < 4; ++ni) {
      int c = wc * 64 + ni * 16 + rr;
      bh[ni] = BsV[cur][c * 8 + sh];
      bl[ni] = BsV[cur][c * 8 + sl];
    }
#pragma unroll
    for (int mi = 0; mi < 4; ++mi)
#pragma unroll
      for (int ni = 0; ni < 4; ++ni) {
        acc[mi][ni] = __builtin_amdgcn_mfma_f32_16x16x32_bf16(ah[mi], bh[ni], acc[mi][ni], 0, 0, 0);
        acc[mi][ni] = __builtin_amdgcn_mfma_f32_16x16x32_bf16(ah[mi], bl[ni], acc[mi][ni], 0, 0, 0);
        acc[mi][ni] = __builtin_amdgcn_mfma_f32_16x16x32_bf16(al[mi], bh[ni], acc[mi][ni], 0, 0, 0);
      }

    __builtin_amdgcn_s_barrier();         // all waves done reading buf[cur]
    if (ktc + 2 < K32) stage(cur, ktc + 2);
    cur ^= 1;
  }

  const int orow = (ln >> 4) * 4;
#pragma unroll
  for (int mi = 0; mi < 4; ++mi)
#pragma unroll
    for (int ni = 0; ni < 4; ++ni) {
      int rowg = m0 + wr * 64 + mi * 16 + orow;
      int colg = n0 + wc * 64 + ni * 16 + rr;
#pragma unroll
      for (int i = 0; i < 4; ++i)
        C[(size_t)(rowg + i) * ldc + colg] = acc[mi][ni][i];
    }
}

// ---------------------------------------------------------------------------
// xdbl split-K MFMA (same counted-vmcnt pipeline): P[kz][4096][96] partials.
// ---------------------------------------------------------------------------
__global__ __launch_bounds__(256, 2) void xdbl_mfma_k(
    const unsigned short* __restrict__ A, const unsigned short* __restrict__ Bt,
    float* __restrict__ P)
{
  __shared__ s16x8 AsV[2][128 * 8];
  __shared__ s16x8 BsV[2][128 * 8];

  const int tid = threadIdx.x;
  const int wv  = tid >> 6;
  const int ln  = tid & 63;
  const int wr  = wv >> 1, wc = wv & 1;
  const int kz  = blockIdx.x;            // 0..7
  const int m0  = blockIdx.y * 128;
  const int K32 = 64;                    // K=2048

  const int rr = ln & 15;
  const int ko = ln >> 4;
  const int sh = ko ^ (rr & 7);
  const int sl = (4 | ko) ^ (rr & 7);
  const int srow  = ln >> 3;
  const int sslot = (ln & 7) ^ srow;

  auto stage = [&](int buf, int ktc) {
#pragma unroll
    for (int t = 0; t < 4; ++t) {
      int i = wv * 4 + t;
      const unsigned short* ga =
          A + ((size_t)(m0 + i * 8 + srow) * K32 + ktc) * 64 + sslot * 8;
      const unsigned short* gb =
          Bt + ((size_t)(i * 8 + srow) * K32 + ktc) * 64 + sslot * 8;
      __builtin_amdgcn_global_load_lds(
          (const __attribute__((address_space(1))) void*)ga,
          (__attribute__((address_space(3))) void*)((char*)&AsV[buf][0] + i * 1024), 16, 0, 0);
      __builtin_amdgcn_global_load_lds(
          (const __attribute__((address_space(1))) void*)gb,
          (__attribute__((address_space(3))) void*)((char*)&BsV[buf][0] + i * 1024), 16, 0, 0);
    }
  };

  f32x4 acc[4][4];
#pragma unroll
  for (int i = 0; i < 4; i++)
#pragma unroll
    for (int j = 0; j < 4; j++) acc[i][j] = (f32x4)0.f;

  const int kbeg = kz * 8, kend = kz * 8 + 8;
  stage(0, kbeg);
  stage(1, kbeg + 1);

  int cur = 0;
  for (int ktc = kbeg; ktc < kend; ++ktc) {
    if (ktc + 1 < kend)
      asm volatile("s_waitcnt vmcnt(8)" ::: "memory");
    else
      asm volatile("s_waitcnt vmcnt(0)" ::: "memory");
    __builtin_amdgcn_s_barrier();

    s16x8 ah[4], al[4], bh[4], bl[4];
#pragma unroll
    for (int mi = 0; mi < 4; ++mi) {
      int r = wr * 64 + mi * 16 + rr;
      ah[mi] = AsV[cur][r * 8 + sh];
      al[mi] = AsV[cur][r * 8 + sl];
    }
#pragma unroll
    for (int ni = 0; ni < 4; ++ni) {
      int c = wc * 64 + ni * 16 + rr;
      bh[ni] = BsV[cur][c * 8 + sh];
      bl[ni] = BsV[cur][c * 8 + sl];
    }
#pragma unroll
    for (int mi = 0; mi < 4; ++mi)
#pragma unroll
      for (int ni = 0; ni < 4; ++ni) {
        acc[mi][ni] = __builtin_amdgcn_mfma_f32_16x16x32_bf16(ah[mi], bh[ni], acc[mi][ni], 0, 0, 0);
        acc[mi][ni] = __builtin_amdgcn_mfma_f32_16x16x32_bf16(ah[mi], bl[ni], acc[mi][ni], 0, 0, 0);
        acc[mi][ni] = __builtin_amdgcn_mfma_f32_16x16x32_bf16(al[mi], bh[ni], acc[mi][ni], 0, 0, 0);
      }

    __builtin_amdgcn_s_barrier();
    if (ktc + 2 < kend) stage(cur, ktc + 2);
    cur ^= 1;
  }

  const int orow = (ln >> 4) * 4;
#pragma unroll
  for (int mi = 0; mi < 4; ++mi)
#pragma unroll
    for (int ni = 0; ni < 4; ++ni) {
      int rowg = m0 + wr * 64 + mi * 16 + orow;
      int colg = wc * 64 + ni * 16 + rr;
      if (colg < 96) {
#pragma unroll
        for (int i = 0; i < 4; ++i)
          P[((size_t)kz * 4096 + rowg + i) * 96 + colg] = acc[mi][ni][i];
      }
    }
}

// xdbl[i] = sum over 8 partial slices
__global__ __launch_bounds__(256) void xdbl_reduce_k(
    const float* __restrict__ P, float* __restrict__ xdbl)
{
  int i = blockIdx.x * 256 + threadIdx.x;   // 0..393215
  float s = 0.f;
#pragma unroll
  for (int kz = 0; kz < 8; ++kz) s += P[(size_t)kz * 393216 + i];
  xdbl[i] = s;
}

// ---------------------------------------------------------------------------
// fp32 GEMM (small K=64 dt projection), EPI==1: softplus(acc + bias[col]).
// ---------------------------------------------------------------------------
template <int EPI>
__global__ __launch_bounds__(256, 2) void sgemm_k(
    const float* __restrict__ A, const float* __restrict__ B,
    const float* __restrict__ bias, float* __restrict__ C,
    int M, int N, int K, int lda, int ldb, int ldc)
{
  __shared__ float As[16][132];
  __shared__ float Bs[16][128];

  const int tid = threadIdx.x;
  const int m0 = blockIdx.y * 128;
  const int n0 = blockIdx.x * 128;
  const int tx = tid & 15;
  const int ty = tid >> 4;

  float acc[2][2][4][4];
#pragma unroll
  for (int a = 0; a < 2; a++)
#pragma unroll
    for (int b2 = 0; b2 < 2; b2++)
#pragma unroll
      for (int i = 0; i < 4; i++)
#pragma unroll
        for (int j = 0; j < 4; j++) acc[a][b2][i][j] = 0.f;

  for (int k0 = 0; k0 < K; k0 += 16) {
#pragma unroll
    for (int t = 0; t < 2; ++t) {
      int i = tid + t * 256;
      int row = i >> 2;
      int kq = (i & 3) * 4;
      float4 v = *(const float4*)(A + (size_t)(m0 + row) * lda + k0 + kq);
      As[kq + 0][row] = v.x; As[kq + 1][row] = v.y;
      As[kq + 2][row] = v.z; As[kq + 3][row] = v.w;
    }
#pragma unroll
    for (int t = 0; t < 2; ++t) {
      int i = tid + t * 256;
      int kr = i >> 5;
      int cq = (i & 31) * 4;
      *(float4*)&Bs[kr][cq] = *(const float4*)(B + (size_t)(k0 + kr) * ldb + n0 + cq);
    }
    __syncthreads();
#pragma unroll
    for (int kk = 0; kk < 16; ++kk) {
      float4 a0 = *(const float4*)&As[kk][ty * 4];
      float4 a1 = *(const float4*)&As[kk][64 + ty * 4];
      float4 b0 = *(const float4*)&Bs[kk][tx * 4];
      float4 b1 = *(const float4*)&Bs[kk][64 + tx * 4];
      float av[2][4] = {{a0.x, a0.y, a0.z, a0.w}, {a1.x, a1.y, a1.z, a1.w}};
      float bv[2][4] = {{b0.x, b0.y, b0.z, b0.w}, {b1.x, b1.y, b1.z, b1.w}};
#pragma unroll
      for (int a = 0; a < 2; a++)
#pragma unroll
        for (int i = 0; i < 4; i++)
#pragma unroll
          for (int b2 = 0; b2 < 2; b2++)
#pragma unroll
            for (int j = 0; j < 4; j++)
              acc[a][b2][i][j] = fmaf(av[a][i], bv[b2][j], acc[a][b2][i][j]);
    }
    __syncthreads();
  }

#pragma unroll
  for (int a = 0; a < 2; a++) {
#pragma unroll
    for (int i = 0; i < 4; i++) {
      int row = m0 + a * 64 + ty * 4 + i;
#pragma unroll
      for (int b2 = 0; b2 < 2; b2++) {
        int col = n0 + b2 * 64 + tx * 4;
        float4 v = make_float4(acc[a][b2][i][0], acc[a][b2][i][1],
                               acc[a][b2][i][2], acc[a][b2][i][3]);
        if (EPI == 1) {
          v.x = softplusf(v.x + bias[col + 0]);
          v.y = softplusf(v.y + bias[col + 1]);
          v.z = softplusf(v.z + bias[col + 2]);
          v.w = softplusf(v.w + bias[col + 3]);
        }
        *(float4*)(C + (size_t)row * ldc + col) = v;
      }
    }
  }
}

// ---------------------------------------------------------------------------
// depthwise causal conv1d (taps=4) + bias + silu  (round-6 version)
// ---------------------------------------------------------------------------
__global__ __launch_bounds__(256) void conv_silu_k(
    const float* __restrict__ xz, const float* __restrict__ cw,
    const float* __restrict__ cb, float* __restrict__ xi)
{
  int idx = blockIdx.x * 256 + threadIdx.x;
  int d = idx & (D_INNER - 1);
  int row = idx >> 11;
  int l = row & (SEQLEN - 1);
  float4 w = *(const float4*)(cw + d * 4);
  const float wv[4] = {w.x, w.y, w.z, w.w};
  float acc = cb[d];
#pragma unroll
  for (int j = 0; j < 4; j++) {
    int ll = l - 3 + j;
    if (ll >= 0)
      acc = fmaf(wv[j], xz[(size_t)(row - 3 + j) * 4096 + d], acc);
  }
  xi[idx] = siluf(acc);
}

__global__ __launch_bounds__(256) void aprep_k(const float* __restrict__ A_log,
                                               float* __restrict__ A2)
{
  int i = blockIdx.x * 256 + threadIdx.x;
  A2[i] = -__expf(A_log[i]);
}

// ---------------------------------------------------------------------------
// chunked selective scan (3 passes) — unchanged
// ---------------------------------------------------------------------------
__global__ __launch_bounds__(256) void scan_pass1(
    const float* __restrict__ dt, const float* __restrict__ xi,
    const float* __restrict__ xdbl, const float* __restrict__ A2,
    float* __restrict__ cP, float* __restrict__ cH)
{
  int d = blockIdx.x * 256 + threadIdx.x;
  int c = blockIdx.y;
  int b = blockIdx.z;
  float a2[D_STATE], h[D_STATE], P[D_STATE];
#pragma unroll
  for (int n = 0; n < D_STATE; n++) {
    a2[n] = A2[d * D_STATE + n];
    h[n] = 0.f;
    P[n] = 1.f;
  }
  int rowbase = b * SEQLEN + c * CHUNKLEN;
  for (int l = 0; l < CHUNKLEN; l++) {
    int row = rowbase + l;
    float dtv = dt[(size_t)row * D_INNER + d];
    float xv = xi[(size_t)row * D_INNER + d];
    float dtx = dtv * xv;
    const float* Bp = xdbl + (size_t)row * 96 + 64;
#pragma unroll
    for (int n = 0; n < D_STATE; n++) {
      float dA = __expf(dtv * a2[n]);
      P[n] *= dA;
      h[n] = fmaf(dA, h[n], dtx * Bp[n]);
    }
  }
  size_t base = ((size_t)(b * D_INNER + d) * NCHUNK + c) * D_STATE;
#pragma unroll
  for (int n = 0; n < D_STATE; n++) {
    cP[base + n] = P[n];
    cH[base + n] = h[n];
  }
}

__global__ __launch_bounds__(256) void scan_pass2(
    const float* __restrict__ cP, float* __restrict__ cH)
{
  int t = blockIdx.x * 256 + threadIdx.x;
  size_t base = (size_t)(t >> 4) * (NCHUNK * D_STATE) + (t & 15);
  float h = 0.f;
  for (int c = 0; c < NCHUNK; c++) {
    size_t idx = base + (size_t)c * D_STATE;
    float Pv = cP[idx];
    float q = cH[idx];
    cH[idx] = h;
    h = fmaf(Pv, h, q);
  }
}

__global__ __launch_bounds__(256) void scan_pass3(
    float* __restrict__ dtyg, const float* __restrict__ xi,
    const float* __restrict__ xdbl, const float* __restrict__ A2,
    const float* __restrict__ cH, const float* __restrict__ Dvec,
    const float* __restrict__ xz)
{
  int d = blockIdx.x * 256 + threadIdx.x;
  int c = blockIdx.y;
  int b = blockIdx.z;
  float a2[D_STATE], h[D_STATE];
  size_t base = ((size_t)(b * D_INNER + d) * NCHUNK + c) * D_STATE;
#pragma unroll
  for (int n = 0; n < D_STATE; n++) {
    a2[n] = A2[d * D_STATE + n];
    h[n] = cH[base + n];
  }
  float Dd = Dvec[d];
  int rowbase = b * SEQLEN + c * CHUNKLEN;
  for (int l = 0; l < CHUNKLEN; l++) {
    int row = rowbase + l;
    float dtv = dtyg[(size_t)row * D_INNER + d];
    float xv = xi[(size_t)row * D_INNER + d];
    float dtx = dtv * xv;
    const float* Bp = xdbl + (size_t)row * 96 + 64;
    const float* Cp = Bp + D_STATE;
    float y = Dd * xv;
#pragma unroll
    for (int n = 0; n < D_STATE; n++) {
      float dA = __expf(dtv * a2[n]);
      h[n] = fmaf(dA, h[n], dtx * Bp[n]);
      y = fmaf(h[n], Cp[n], y);
    }
    float z = xz[(size_t)row * 4096 + D_INNER + d];
    dtyg[(size_t)row * D_INNER + d] = y * siluf(z);
  }
}

// ---------------------------------------------------------------------------
extern "C" void kernel_launch(void* const* d_in, const int* in_sizes, int n_in,
                              void* d_out, int out_size, void* d_ws,
                              size_t ws_size, hipStream_t stream)
{
  const float* x     = (const float*)d_in[0];
  const float* W_in  = (const float*)d_in[1];
  const float* cw    = (const float*)d_in[2];
  const float* cb    = (const float*)d_in[3];
  const float* W_x   = (const float*)d_in[4];
  const float* W_dt  = (const float*)d_in[5];
  const float* b_dt  = (const float*)d_in[6];
  const float* A_log = (const float*)d_in[7];
  const float* Dv    = (const float*)d_in[8];
  const float* W_out = (const float*)d_in[9];
  float* out = (float*)d_out;

  float* ws    = (float*)d_ws;
  float* xz    = ws;                       // 16,777,216
  float* xi    = xz + 16777216;            //  8,388,608
  float* xdbl  = xi + 8388608;             //    393,216
  float* dtyg  = xdbl + 393216;            //  8,388,608
  float* A2    = dtyg + 8388608;           //     32,768
  float* cP    = A2 + 32768;               //  2,097,152
  float* cH    = cP + 2097152;             //  2,097,152

  // packed hi/lo bf16 + partial overlays
  unsigned* WinTP  = (unsigned*)dtyg;                 // GEMM1 B (dead after)
  unsigned* xP     = (unsigned*)(dtyg + 4194304);     // GEMM1 A (dead after)
  unsigned* xiP    = (unsigned*)dtyg;                 // xdbl-GEMM A (dead after)
  unsigned* WxTP   = (unsigned*)xdbl;                 // xdbl-GEMM B (dead before reduce)
  float*    Ppart  = cP;                              // [8][4096][96] spans cP+cH
  unsigned* ygP    = (unsigned*)xi;                   // GEMM2 A (xi dead post-scan)
  unsigned* WoutTP = (unsigned*)cP;                   // GEMM2 B (cP dead post-pass2)

  aprep_k<<<128, 256, 0, stream>>>(A_log, A2);

  // W_in (1024x4096) -> transposed+packed WinTP; x -> packed xP
  transpack_k<<<dim3(16, 32), 256, 0, stream>>>(W_in, WinTP, 1024, 4096);
  packsplit_k<<<512, 256, 0, stream>>>(x, xP);

  // xz = x @ W_in   (4096x4096, K=1024)
  mgemm_split<<<dim3(32, 32), 256, 0, stream>>>(
      (const unsigned short*)xP, (const unsigned short*)WinTP, xz,
      4096, 4096, 1024, 4096);

  conv_silu_k<<<32768, 256, 0, stream>>>(xz, cw, cb, xi);

  // x_dbl = xi @ W_x via packed split-bf16 MFMA, split-K=8, private partials
  packsplit_k<<<1024, 256, 0, stream>>>(xi, xiP);
  transpack_wx_k<<<64, 128, 0, stream>>>(W_x, WxTP);
  xdbl_mfma_k<<<dim3(8, 32), 256, 0, stream>>>(
      (const unsigned short*)xiP, (const unsigned short*)WxTP, Ppart);
  xdbl_reduce_k<<<1536, 256, 0, stream>>>(Ppart, xdbl);

  // dt = softplus(x_dbl[:, :64] @ W_dt + b_dt)  (K=64, fp32)
  sgemm_k<1><<<dim3(16, 32), 256, 0, stream>>>(xdbl, W_dt, b_dt, dtyg,
                                               4096, 2048, 64, 96, 2048, 2048);

  scan_pass1<<<dim3(8, NCHUNK, NBATCH), 256, 0, stream>>>(dtyg, xi, xdbl, A2, cP, cH);
  scan_pass2<<<256, 256, 0, stream>>>(cP, cH);
  scan_pass3<<<dim3(8, NCHUNK, NBATCH), 256, 0, stream>>>(dtyg, xi, xdbl, A2, cH, Dv, xz);

  // yg -> packed; W_out -> transposed+packed
  packsplit_k<<<1024, 256, 0, stream>>>(dtyg, ygP);
  transpack_k<<<dim3(4, 64), 256, 0, stream>>>(W_out, WoutTP, 2048, 1024);

  // out = yg @ W_out  (4096x1024, K=2048)
  mgemm_split<<<dim3(8, 32), 256, 0, stream>>>(
      (const unsigned short*)ygP, (const unsigned short*)WoutTP, out,
      4096, 1024, 2048, 1024);
}

// Round 10
// 486.597 us; speedup vs baseline: 1.1007x; 1.0512x over previous
//
#include <hip/hip_runtime.h>
#include <math.h>

// ---------------------------------------------------------------------------
// SelectiveSSM (Mamba block) for MI355X — round 10:
//  * GEMM K-loops reverted to round-6 single-buffered form (counted-vmcnt
//    pipeline was neutral-to-negative; schedule iteration stopped).
//  * dt projection (was 125 µs fp32 latency-bound sgemm_k) moved to the
//    packed split-bf16 MFMA GEMM with fused softplus+bias epilogue.
//
// ws layout (floats) — same 152.7 MB as verified round-0 layout:
//   xz    : 16,777,216   (xi_raw 0..2047 | z 2048..4095)
//   xi    :  8,388,608   (post conv+silu; reused as ygP after pass3)
//   xdbl  :    393,216   (WxTP first, then dt_lin | B | C)
//   dtyg  :  8,388,608   (WinTP+xP -> xiP -> dt -> yg)
//   A2    :     32,768
//   cP    :  2,097,152   (Ppart spans cP+cH -> xdblP+WdtTP -> scan products
//   cH    :  2,097,152    -> cP reused as WoutTP after pass2)
// ---------------------------------------------------------------------------

#define D_INNER 2048
#define D_STATE 16
#define SEQLEN  2048
#define NBATCH  2
#define NCHUNK  32
#define CHUNKLEN (SEQLEN / NCHUNK)   // 64

using f32x4 = __attribute__((ext_vector_type(4))) float;
using s16x8 = __attribute__((ext_vector_type(8))) short;

__device__ __forceinline__ float siluf(float x) {
  return x / (1.f + __expf(-x));
}
__device__ __forceinline__ float softplusf(float x) {
  return fmaxf(x, 0.f) + log1pf(__expf(-fabsf(x)));
}

// hi = truncate-to-bf16 (residual exact), lo = RNE-bf16(residual).
__device__ __forceinline__ void split_pair(float f0, float f1,
                                           unsigned& hw, unsigned& lw) {
  unsigned b0 = __float_as_uint(f0), b1 = __float_as_uint(f1);
  hw = (b0 >> 16) | (b1 & 0xFFFF0000u);
  float r0 = f0 - __uint_as_float(b0 & 0xFFFF0000u);
  float r1 = f1 - __uint_as_float(b1 & 0xFFFF0000u);
  unsigned c0 = __float_as_uint(r0); c0 += 0x7FFFu + ((c0 >> 16) & 1u);
  unsigned c1 = __float_as_uint(r1); c1 += 0x7FFFu + ((c1 >> 16) & 1u);
  lw = (c0 >> 16) | (c1 & 0xFFFF0000u);
}

// ---------------------------------------------------------------------------
// packsplit: in[R][K] fp32 row-major -> packed [32hi|32lo] bf16 chunks.
// ---------------------------------------------------------------------------
__global__ __launch_bounds__(256) void packsplit_k(
    const float* __restrict__ in, unsigned* __restrict__ out)
{
  size_t g = (size_t)blockIdx.x * 256 + threadIdx.x;
  float f[32];
#pragma unroll
  for (int q = 0; q < 8; ++q)
    *(float4*)&f[q * 4] = *(const float4*)(in + g * 32 + q * 4);
  unsigned* o = out + g * 32;
#pragma unroll
  for (int j = 0; j < 16; ++j) {
    unsigned hw, lw;
    split_pair(f[2 * j], f[2 * j + 1], hw, lw);
    o[j] = hw; o[16 + j] = lw;
  }
}

// ---------------------------------------------------------------------------
// packsplit for dt input: xdbl[4096][96] cols 0..63 -> packed [4096][2][64].
// chunk g = row*2 + kc; 8192 chunks -> 32 blocks.
// ---------------------------------------------------------------------------
__global__ __launch_bounds__(256) void packsplit_dt_k(
    const float* __restrict__ xdbl, unsigned* __restrict__ out)
{
  int g = blockIdx.x * 256 + threadIdx.x;   // < 8192
  int row = g >> 1, kc = g & 1;
  float f[32];
#pragma unroll
  for (int q = 0; q < 8; ++q)
    *(float4*)&f[q * 4] =
        *(const float4*)(xdbl + (size_t)row * 96 + kc * 32 + q * 4);
  unsigned* o = out + (size_t)g * 32;
#pragma unroll
  for (int j = 0; j < 16; ++j) {
    unsigned hw, lw;
    split_pair(f[2 * j], f[2 * j + 1], hw, lw);
    o[j] = hw; o[16 + j] = lw;
  }
}

// ---------------------------------------------------------------------------
// transpack: in[K][N] fp32 row-major (weights) -> out packed [N][K/32][64].
// ---------------------------------------------------------------------------
__global__ __launch_bounds__(256) void transpack_k(
    const float* __restrict__ in, unsigned* __restrict__ out, int K, int N)
{
  __shared__ float tile[32][257];
  const int tid = threadIdx.x;
  const int nb = blockIdx.x * 256;
  const int kc = blockIdx.y;
#pragma unroll 8
  for (int ky = 0; ky < 32; ++ky)
    tile[ky][tid] = in[(size_t)(kc * 32 + ky) * N + nb + tid];
  __syncthreads();
  unsigned* o = out + ((size_t)(nb + tid) * (K >> 5) + kc) * 32;
#pragma unroll
  for (int j = 0; j < 16; ++j) {
    unsigned hw, lw;
    split_pair(tile[2 * j][tid], tile[2 * j + 1][tid], hw, lw);
    o[j] = hw; o[16 + j] = lw;
  }
}

// ---------------------------------------------------------------------------
// transpack for W_x: in[2048][96] -> packed [128][64][64], rows 96..127 zero.
// ---------------------------------------------------------------------------
__global__ __launch_bounds__(128) void transpack_wx_k(
    const float* __restrict__ Wx, unsigned* __restrict__ out)
{
  const int n = threadIdx.x;     // 0..127
  const int kc = blockIdx.x;     // 0..63
  float f[32];
#pragma unroll
  for (int j = 0; j < 32; ++j)
    f[j] = (n < 96) ? Wx[(size_t)(kc * 32 + j) * 96 + n] : 0.f;
  unsigned* o = out + ((size_t)n * 64 + kc) * 32;
#pragma unroll
  for (int j = 0; j < 16; ++j) {
    unsigned hw, lw;
    split_pair(f[2 * j], f[2 * j + 1], hw, lw);
    o[j] = hw; o[16 + j] = lw;
  }
}

// ---------------------------------------------------------------------------
// Split-bf16 MFMA GEMM (round-6 single-buffered loop, verified 92 µs @K=1024).
// C[M,N] = A[M,K] @ Bt[N,K]^T; operands packed [row][K/32][32hi|32lo] bf16.
// LDS phys slot = un-slot ^ (row&7); staging source pre-swizzled (rule 21);
// fragment reads are bank-minimum ds_read_b128.
// acc += ah*bh + ah*bl + al*bh.
// EPI==1: C = softplus(acc + bias[col]) fused epilogue.
// ---------------------------------------------------------------------------
template <int EPI>
__global__ __launch_bounds__(256, 2) void mgemm_split(
    const unsigned short* __restrict__ A, const unsigned short* __restrict__ Bt,
    const float* __restrict__ bias, float* __restrict__ C,
    int M, int N, int K, int ldc)
{
  __shared__ s16x8 AsV[128 * 8];   // 16 KB
  __shared__ s16x8 BsV[128 * 8];   // 16 KB

  const int tid = threadIdx.x;
  const int wv  = tid >> 6;
  const int ln  = tid & 63;
  const int wr  = wv >> 1, wc = wv & 1;
  const int m0  = blockIdx.y * 128, n0 = blockIdx.x * 128;
  const int K32 = K >> 5;

  const int rr = ln & 15;
  const int ko = ln >> 4;
  const int sh = ko ^ (rr & 7);
  const int sl = (4 | ko) ^ (rr & 7);
  const int srow  = ln >> 3;
  const int sslot = (ln & 7) ^ srow;

  f32x4 acc[4][4];
#pragma unroll
  for (int i = 0; i < 4; i++)
#pragma unroll
    for (int j = 0; j < 4; j++) acc[i][j] = (f32x4)0.f;

  for (int ktc = 0; ktc < K32; ++ktc) {
    __syncthreads();
#pragma unroll
    for (int t = 0; t < 4; ++t) {
      int i = wv * 4 + t;
      const unsigned short* ga =
          A + ((size_t)(m0 + i * 8 + srow) * K32 + ktc) * 64 + sslot * 8;
      const unsigned short* gb =
          Bt + ((size_t)(n0 + i * 8 + srow) * K32 + ktc) * 64 + sslot * 8;
      __builtin_amdgcn_global_load_lds(
          (const __attribute__((address_space(1))) void*)ga,
          (__attribute__((address_space(3))) void*)((char*)AsV + i * 1024), 16, 0, 0);
      __builtin_amdgcn_global_load_lds(
          (const __attribute__((address_space(1))) void*)gb,
          (__attribute__((address_space(3))) void*)((char*)BsV + i * 1024), 16, 0, 0);
    }
    __syncthreads();

    s16x8 ah[4], al[4], bh[4], bl[4];
#pragma unroll
    for (int mi = 0; mi < 4; ++mi) {
      int r = wr * 64 + mi * 16 + rr;
      ah[mi] = AsV[r * 8 + sh];
      al[mi] = AsV[r * 8 + sl];
    }
#pragma unroll
    for (int ni = 0; ni < 4; ++ni) {
      int c = wc * 64 + ni * 16 + rr;
      bh[ni] = BsV[c * 8 + sh];
      bl[ni] = BsV[c * 8 + sl];
    }
#pragma unroll
    for (int mi = 0; mi < 4; ++mi)
#pragma unroll
      for (int ni = 0; ni < 4; ++ni) {
        acc[mi][ni] = __builtin_amdgcn_mfma_f32_16x16x32_bf16(ah[mi], bh[ni], acc[mi][ni], 0, 0, 0);
        acc[mi][ni] = __builtin_amdgcn_mfma_f32_16x16x32_bf16(ah[mi], bl[ni], acc[mi][ni], 0, 0, 0);
        acc[mi][ni] = __builtin_amdgcn_mfma_f32_16x16x32_bf16(al[mi], bh[ni], acc[mi][ni], 0, 0, 0);
      }
  }

  const int orow = (ln >> 4) * 4;
#pragma unroll
  for (int mi = 0; mi < 4; ++mi)
#pragma unroll
    for (int ni = 0; ni < 4; ++ni) {
      int rowg = m0 + wr * 64 + mi * 16 + orow;
      int colg = n0 + wc * 64 + ni * 16 + rr;
      float bcol = (EPI == 1) ? bias[colg] : 0.f;
#pragma unroll
      for (int i = 0; i < 4; ++i) {
        float v = acc[mi][ni][i];
        if (EPI == 1) v = softplusf(v + bcol);
        C[(size_t)(rowg + i) * ldc + colg] = v;
      }
    }
}

// ---------------------------------------------------------------------------
// xdbl split-K MFMA (round-6 single-buffered): P[kz][4096][96] partials.
// ---------------------------------------------------------------------------
__global__ __launch_bounds__(256, 2) void xdbl_mfma_k(
    const unsigned short* __restrict__ A, const unsigned short* __restrict__ Bt,
    float* __restrict__ P)
{
  __shared__ s16x8 AsV[128 * 8];
  __shared__ s16x8 BsV[128 * 8];

  const int tid = threadIdx.x;
  const int wv  = tid >> 6;
  const int ln  = tid & 63;
  const int wr  = wv >> 1, wc = wv & 1;
  const int kz  = blockIdx.x;            // 0..7
  const int m0  = blockIdx.y * 128;
  const int K32 = 64;                    // K=2048

  const int rr = ln & 15;
  const int ko = ln >> 4;
  const int sh = ko ^ (rr & 7);
  const int sl = (4 | ko) ^ (rr & 7);
  const int srow  = ln >> 3;
  const int sslot = (ln & 7) ^ srow;

  f32x4 acc[4][4];
#pragma unroll
  for (int i = 0; i < 4; i++)
#pragma unroll
    for (int j = 0; j < 4; j++) acc[i][j] = (f32x4)0.f;

  for (int ktc = kz * 8; ktc < kz * 8 + 8; ++ktc) {
    __syncthreads();
#pragma unroll
    for (int t = 0; t < 4; ++t) {
      int i = wv * 4 + t;
      const unsigned short* ga =
          A + ((size_t)(m0 + i * 8 + srow) * K32 + ktc) * 64 + sslot * 8;
      const unsigned short* gb =
          Bt + ((size_t)(i * 8 + srow) * K32 + ktc) * 64 + sslot * 8;
      __builtin_amdgcn_global_load_lds(
          (const __attribute__((address_space(1))) void*)ga,
          (__attribute__((address_space(3))) void*)((char*)AsV + i * 1024), 16, 0, 0);
      __builtin_amdgcn_global_load_lds(
          (const __attribute__((address_space(1))) void*)gb,
          (__attribute__((address_space(3))) void*)((char*)BsV + i * 1024), 16, 0, 0);
    }
    __syncthreads();

    s16x8 ah[4], al[4], bh[4], bl[4];
#pragma unroll
    for (int mi = 0; mi < 4; ++mi) {
      int r = wr * 64 + mi * 16 + rr;
      ah[mi] = AsV[r * 8 + sh];
      al[mi] = AsV[r * 8 + sl];
    }
#pragma unroll
    for (int ni = 0; ni < 4; ++ni) {
      int c = wc * 64 + ni * 16 + rr;
      bh[ni] = BsV[c * 8 + sh];
      bl[ni] = BsV[c * 8 + sl];
    }
#pragma unroll
    for (int mi = 0; mi < 4; ++mi)
#pragma unroll
      for (int ni = 0; ni < 4; ++ni) {
        acc[mi][ni] = __builtin_amdgcn_mfma_f32_16x16x32_bf16(ah[mi], bh[ni], acc[mi][ni], 0, 0, 0);
        acc[mi][ni] = __builtin_amdgcn_mfma_f32_16x16x32_bf16(ah[mi], bl[ni], acc[mi][ni], 0, 0, 0);
        acc[mi][ni] = __builtin_amdgcn_mfma_f32_16x16x32_bf16(al[mi], bh[ni], acc[mi][ni], 0, 0, 0);
      }
  }

  const int orow = (ln >> 4) * 4;
#pragma unroll
  for (int mi = 0; mi < 4; ++mi)
#pragma unroll
    for (int ni = 0; ni < 4; ++ni) {
      int rowg = m0 + wr * 64 + mi * 16 + orow;
      int colg = wc * 64 + ni * 16 + rr;
      if (colg < 96) {
#pragma unroll
        for (int i = 0; i < 4; ++i)
          P[((size_t)kz * 4096 + rowg + i) * 96 + colg] = acc[mi][ni][i];
      }
    }
}

// xdbl[i] = sum over 8 partial slices
__global__ __launch_bounds__(256) void xdbl_reduce_k(
    const float* __restrict__ P, float* __restrict__ xdbl)
{
  int i = blockIdx.x * 256 + threadIdx.x;   // 0..393215
  float s = 0.f;
#pragma unroll
  for (int kz = 0; kz < 8; ++kz) s += P[(size_t)kz * 393216 + i];
  xdbl[i] = s;
}

// ---------------------------------------------------------------------------
// depthwise causal conv1d (taps=4) + bias + silu
// ---------------------------------------------------------------------------
__global__ __launch_bounds__(256) void conv_silu_k(
    const float* __restrict__ xz, const float* __restrict__ cw,
    const float* __restrict__ cb, float* __restrict__ xi)
{
  int idx = blockIdx.x * 256 + threadIdx.x;
  int d = idx & (D_INNER - 1);
  int row = idx >> 11;
  int l = row & (SEQLEN - 1);
  float4 w = *(const float4*)(cw + d * 4);
  const float wv[4] = {w.x, w.y, w.z, w.w};
  float acc = cb[d];
#pragma unroll
  for (int j = 0; j < 4; j++) {
    int ll = l - 3 + j;
    if (ll >= 0)
      acc = fmaf(wv[j], xz[(size_t)(row - 3 + j) * 4096 + d], acc);
  }
  xi[idx] = siluf(acc);
}

__global__ __launch_bounds__(256) void aprep_k(const float* __restrict__ A_log,
                                               float* __restrict__ A2)
{
  int i = blockIdx.x * 256 + threadIdx.x;
  A2[i] = -__expf(A_log[i]);
}

// ---------------------------------------------------------------------------
// chunked selective scan (3 passes) — unchanged
// ---------------------------------------------------------------------------
__global__ __launch_bounds__(256) void scan_pass1(
    const float* __restrict__ dt, const float* __restrict__ xi,
    const float* __restrict__ xdbl, const float* __restrict__ A2,
    float* __restrict__ cP, float* __restrict__ cH)
{
  int d = blockIdx.x * 256 + threadIdx.x;
  int c = blockIdx.y;
  int b = blockIdx.z;
  float a2[D_STATE], h[D_STATE], P[D_STATE];
#pragma unroll
  for (int n = 0; n < D_STATE; n++) {
    a2[n] = A2[d * D_STATE + n];
    h[n] = 0.f;
    P[n] = 1.f;
  }
  int rowbase = b * SEQLEN + c * CHUNKLEN;
  for (int l = 0; l < CHUNKLEN; l++) {
    int row = rowbase + l;
    float dtv = dt[(size_t)row * D_INNER + d];
    float xv = xi[(size_t)row * D_INNER + d];
    float dtx = dtv * xv;
    const float* Bp = xdbl + (size_t)row * 96 + 64;
#pragma unroll
    for (int n = 0; n < D_STATE; n++) {
      float dA = __expf(dtv * a2[n]);
      P[n] *= dA;
      h[n] = fmaf(dA, h[n], dtx * Bp[n]);
    }
  }
  size_t base = ((size_t)(b * D_INNER + d) * NCHUNK + c) * D_STATE;
#pragma unroll
  for (int n = 0; n < D_STATE; n++) {
    cP[base + n] = P[n];
    cH[base + n] = h[n];
  }
}

__global__ __launch_bounds__(256) void scan_pass2(
    const float* __restrict__ cP, float* __restrict__ cH)
{
  int t = blockIdx.x * 256 + threadIdx.x;
  size_t base = (size_t)(t >> 4) * (NCHUNK * D_STATE) + (t & 15);
  float h = 0.f;
  for (int c = 0; c < NCHUNK; c++) {
    size_t idx = base + (size_t)c * D_STATE;
    float Pv = cP[idx];
    float q = cH[idx];
    cH[idx] = h;
    h = fmaf(Pv, h, q);
  }
}

__global__ __launch_bounds__(256) void scan_pass3(
    float* __restrict__ dtyg, const float* __restrict__ xi,
    const float* __restrict__ xdbl, const float* __restrict__ A2,
    const float* __restrict__ cH, const float* __restrict__ Dvec,
    const float* __restrict__ xz)
{
  int d = blockIdx.x * 256 + threadIdx.x;
  int c = blockIdx.y;
  int b = blockIdx.z;
  float a2[D_STATE], h[D_STATE];
  size_t base = ((size_t)(b * D_INNER + d) * NCHUNK + c) * D_STATE;
#pragma unroll
  for (int n = 0; n < D_STATE; n++) {
    a2[n] = A2[d * D_STATE + n];
    h[n] = cH[base + n];
  }
  float Dd = Dvec[d];
  int rowbase = b * SEQLEN + c * CHUNKLEN;
  for (int l = 0; l < CHUNKLEN; l++) {
    int row = rowbase + l;
    float dtv = dtyg[(size_t)row * D_INNER + d];
    float xv = xi[(size_t)row * D_INNER + d];
    float dtx = dtv * xv;
    const float* Bp = xdbl + (size_t)row * 96 + 64;
    const float* Cp = Bp + D_STATE;
    float y = Dd * xv;
#pragma unroll
    for (int n = 0; n < D_STATE; n++) {
      float dA = __expf(dtv * a2[n]);
      h[n] = fmaf(dA, h[n], dtx * Bp[n]);
      y = fmaf(h[n], Cp[n], y);
    }
    float z = xz[(size_t)row * 4096 + D_INNER + d];
    dtyg[(size_t)row * D_INNER + d] = y * siluf(z);
  }
}

// ---------------------------------------------------------------------------
extern "C" void kernel_launch(void* const* d_in, const int* in_sizes, int n_in,
                              void* d_out, int out_size, void* d_ws,
                              size_t ws_size, hipStream_t stream)
{
  const float* x     = (const float*)d_in[0];
  const float* W_in  = (const float*)d_in[1];
  const float* cw    = (const float*)d_in[2];
  const float* cb    = (const float*)d_in[3];
  const float* W_x   = (const float*)d_in[4];
  const float* W_dt  = (const float*)d_in[5];
  const float* b_dt  = (const float*)d_in[6];
  const float* A_log = (const float*)d_in[7];
  const float* Dv    = (const float*)d_in[8];
  const float* W_out = (const float*)d_in[9];
  float* out = (float*)d_out;

  float* ws    = (float*)d_ws;
  float* xz    = ws;                       // 16,777,216
  float* xi    = xz + 16777216;            //  8,388,608
  float* xdbl  = xi + 8388608;             //    393,216
  float* dtyg  = xdbl + 393216;            //  8,388,608
  float* A2    = dtyg + 8388608;           //     32,768
  float* cP    = A2 + 32768;               //  2,097,152
  float* cH    = cP + 2097152;             //  2,097,152

  // packed hi/lo bf16 + partial overlays
  unsigned* WinTP  = (unsigned*)dtyg;                 // GEMM1 B (dead after)
  unsigned* xP     = (unsigned*)(dtyg + 4194304);     // GEMM1 A (dead after)
  unsigned* xiP    = (unsigned*)dtyg;                 // xdbl-GEMM A (dead after)
  unsigned* WxTP   = (unsigned*)xdbl;                 // xdbl-GEMM B (dead before reduce)
  float*    Ppart  = cP;                              // [8][4096][96] spans cP+cH
  unsigned* xdblP  = (unsigned*)cP;                   // dt-GEMM A (Ppart dead post-reduce)
  unsigned* WdtTP  = (unsigned*)cP + 262144;          // dt-GEMM B (0.5 MB)
  unsigned* ygP    = (unsigned*)xi;                   // GEMM2 A (xi dead post-scan)
  unsigned* WoutTP = (unsigned*)cP;                   // GEMM2 B (cP dead post-pass2)

  aprep_k<<<128, 256, 0, stream>>>(A_log, A2);

  // W_in (1024x4096) -> transposed+packed WinTP; x -> packed xP
  transpack_k<<<dim3(16, 32), 256, 0, stream>>>(W_in, WinTP, 1024, 4096);
  packsplit_k<<<512, 256, 0, stream>>>(x, xP);

  // xz = x @ W_in   (4096x4096, K=1024)
  mgemm_split<0><<<dim3(32, 32), 256, 0, stream>>>(
      (const unsigned short*)xP, (const unsigned short*)WinTP, nullptr, xz,
      4096, 4096, 1024, 4096);

  conv_silu_k<<<32768, 256, 0, stream>>>(xz, cw, cb, xi);

  // x_dbl = xi @ W_x via packed split-bf16 MFMA, split-K=8, private partials
  packsplit_k<<<1024, 256, 0, stream>>>(xi, xiP);
  transpack_wx_k<<<64, 128, 0, stream>>>(W_x, WxTP);
  xdbl_mfma_k<<<dim3(8, 32), 256, 0, stream>>>(
      (const unsigned short*)xiP, (const unsigned short*)WxTP, Ppart);
  xdbl_reduce_k<<<1536, 256, 0, stream>>>(Ppart, xdbl);

  // dt = softplus(x_dbl[:, :64] @ W_dt + b_dt) via packed split-bf16 MFMA
  // (Ppart dead after reduce -> xdblP/WdtTP live in cP region until pass1)
  packsplit_dt_k<<<32, 256, 0, stream>>>(xdbl, xdblP);
  transpack_k<<<dim3(8, 2), 256, 0, stream>>>(W_dt, WdtTP, 64, 2048);
  mgemm_split<1><<<dim3(16, 32), 256, 0, stream>>>(
      (const unsigned short*)xdblP, (const unsigned short*)WdtTP, b_dt, dtyg,
      4096, 2048, 64, 2048);

  scan_pass1<<<dim3(8, NCHUNK, NBATCH), 256, 0, stream>>>(dtyg, xi, xdbl, A2, cP, cH);
  scan_pass2<<<256, 256, 0, stream>>>(cP, cH);
  scan_pass3<<<dim3(8, NCHUNK, NBATCH), 256, 0, stream>>>(dtyg, xi, xdbl, A2, cH, Dv, xz);

  // yg -> packed; W_out -> transposed+packed
  packsplit_k<<<1024, 256, 0, stream>>>(dtyg, ygP);
  transpack_k<<<dim3(4, 64), 256, 0, stream>>>(W_out, WoutTP, 2048, 1024);

  // out = yg @ W_out  (4096x1024, K=2048)
  mgemm_split<0><<<dim3(8, 32), 256, 0, stream>>>(
      (const unsigned short*)ygP, (const unsigned short*)WoutTP, nullptr, out,
      4096, 1024, 2048, 1024);
}

// Round 11
// 450.741 us; speedup vs baseline: 1.1883x; 1.0795x over previous
//
#include <hip/hip_runtime.h>
#include <math.h>

// ---------------------------------------------------------------------------
// SelectiveSSM (Mamba block) for MI355X — round 11: producer-side packing.
//  * conv+silu emits packed xiP directly (packsplit(xi) deleted)
//  * scan_pass3 emits packed yg into xz's dead xi_raw half (packsplit(yg)
//    deleted; GEMM2 reads A with row stride 128 chunks)
//  * xdbl reduce + dt-input packing fused (one kernel); packed dt operands
//    live in the dead tail after Ppart
//  * aprep folded into scan passes
// GEMM structure frozen at the round-6 verified form (schedule iteration
// stopped per round-9 decision rule).
//
// ws layout (floats) — same 152.7 MB:
//   xz    : 16,777,216   (xi_raw | z; xi_raw half reused as packed ygP)
//   xi    :  8,388,608   (fp32, read by scan)
//   xdbl  :    393,216   (WxTP first; then fp32 B|C cols 64..95)
//   dtyg  :  8,388,608   (WinTP+xP -> xiP -> dt fp32)
//   A2    :     32,768   (unused, layout anchor)
//   cP    :  2,097,152   } Ppart[8][4096][96] spans cP+cH (12.6 MB);
//   cH    :  2,097,152   } tail [cP+3145728, +1.5MB) = xdblP + WdtTP;
//                          then scan products; cP = WoutTP after pass2
// ---------------------------------------------------------------------------

#define D_INNER 2048
#define D_STATE 16
#define SEQLEN  2048
#define NBATCH  2
#define NCHUNK  32
#define CHUNKLEN (SEQLEN / NCHUNK)   // 64

using f32x4 = __attribute__((ext_vector_type(4))) float;
using s16x8 = __attribute__((ext_vector_type(8))) short;

__device__ __forceinline__ float siluf(float x) {
  return x / (1.f + __expf(-x));
}
__device__ __forceinline__ float softplusf(float x) {
  return fmaxf(x, 0.f) + log1pf(__expf(-fabsf(x)));
}

// hi = truncate-to-bf16 (residual exact), lo = RNE-bf16(residual).
__device__ __forceinline__ void split_pair(float f0, float f1,
                                           unsigned& hw, unsigned& lw) {
  unsigned b0 = __float_as_uint(f0), b1 = __float_as_uint(f1);
  hw = (b0 >> 16) | (b1 & 0xFFFF0000u);
  float r0 = f0 - __uint_as_float(b0 & 0xFFFF0000u);
  float r1 = f1 - __uint_as_float(b1 & 0xFFFF0000u);
  unsigned c0 = __float_as_uint(r0); c0 += 0x7FFFu + ((c0 >> 16) & 1u);
  unsigned c1 = __float_as_uint(r1); c1 += 0x7FFFu + ((c1 >> 16) & 1u);
  lw = (c0 >> 16) | (c1 & 0xFFFF0000u);
}

// scalar version: hi/lo u16 for one float (same math as split_pair)
__device__ __forceinline__ void split_one(float v, unsigned short& hv,
                                          unsigned short& lv) {
  unsigned b = __float_as_uint(v);
  hv = (unsigned short)(b >> 16);
  float r = v - __uint_as_float(b & 0xFFFF0000u);
  unsigned c = __float_as_uint(r);
  c += 0x7FFFu + ((c >> 16) & 1u);
  lv = (unsigned short)(c >> 16);
}

// ---------------------------------------------------------------------------
// packsplit: in[R][K] fp32 row-major -> packed [32hi|32lo] bf16 chunks.
// (still used for input x)
// ---------------------------------------------------------------------------
__global__ __launch_bounds__(256) void packsplit_k(
    const float* __restrict__ in, unsigned* __restrict__ out)
{
  size_t g = (size_t)blockIdx.x * 256 + threadIdx.x;
  float f[32];
#pragma unroll
  for (int q = 0; q < 8; ++q)
    *(float4*)&f[q * 4] = *(const float4*)(in + g * 32 + q * 4);
  unsigned* o = out + g * 32;
#pragma unroll
  for (int j = 0; j < 16; ++j) {
    unsigned hw, lw;
    split_pair(f[2 * j], f[2 * j + 1], hw, lw);
    o[j] = hw; o[16 + j] = lw;
  }
}

// ---------------------------------------------------------------------------
// transpack: in[K][N] fp32 row-major (weights) -> out packed [N][K/32][64].
// ---------------------------------------------------------------------------
__global__ __launch_bounds__(256) void transpack_k(
    const float* __restrict__ in, unsigned* __restrict__ out, int K, int N)
{
  __shared__ float tile[32][257];
  const int tid = threadIdx.x;
  const int nb = blockIdx.x * 256;
  const int kc = blockIdx.y;
#pragma unroll 8
  for (int ky = 0; ky < 32; ++ky)
    tile[ky][tid] = in[(size_t)(kc * 32 + ky) * N + nb + tid];
  __syncthreads();
  unsigned* o = out + ((size_t)(nb + tid) * (K >> 5) + kc) * 32;
#pragma unroll
  for (int j = 0; j < 16; ++j) {
    unsigned hw, lw;
    split_pair(tile[2 * j][tid], tile[2 * j + 1][tid], hw, lw);
    o[j] = hw; o[16 + j] = lw;
  }
}

// ---------------------------------------------------------------------------
// transpack for W_x: in[2048][96] -> packed [128][64][64], rows 96..127 zero.
// ---------------------------------------------------------------------------
__global__ __launch_bounds__(128) void transpack_wx_k(
    const float* __restrict__ Wx, unsigned* __restrict__ out)
{
  const int n = threadIdx.x;     // 0..127
  const int kc = blockIdx.x;     // 0..63
  float f[32];
#pragma unroll
  for (int j = 0; j < 32; ++j)
    f[j] = (n < 96) ? Wx[(size_t)(kc * 32 + j) * 96 + n] : 0.f;
  unsigned* o = out + ((size_t)n * 64 + kc) * 32;
#pragma unroll
  for (int j = 0; j < 16; ++j) {
    unsigned hw, lw;
    split_pair(f[2 * j], f[2 * j + 1], hw, lw);
    o[j] = hw; o[16 + j] = lw;
  }
}

// ---------------------------------------------------------------------------
// Split-bf16 MFMA GEMM (round-6 verified single-buffered loop).
// C[M,N] = A[M,K] @ Bt[N,K]^T; operands packed [row][chunks][32hi|32lo] bf16.
// ldaC = A row stride in 128B chunks (K32 for dense, 128 for yg-in-xz).
// EPI==1: C = softplus(acc + bias[col]) fused epilogue.
// ---------------------------------------------------------------------------
template <int EPI>
__global__ __launch_bounds__(256, 2) void mgemm_split(
    const unsigned short* __restrict__ A, const unsigned short* __restrict__ Bt,
    const float* __restrict__ bias, float* __restrict__ C,
    int M, int N, int K, int ldaC, int ldc)
{
  __shared__ s16x8 AsV[128 * 8];   // 16 KB
  __shared__ s16x8 BsV[128 * 8];   // 16 KB

  const int tid = threadIdx.x;
  const int wv  = tid >> 6;
  const int ln  = tid & 63;
  const int wr  = wv >> 1, wc = wv & 1;
  const int m0  = blockIdx.y * 128, n0 = blockIdx.x * 128;
  const int K32 = K >> 5;

  const int rr = ln & 15;
  const int ko = ln >> 4;
  const int sh = ko ^ (rr & 7);
  const int sl = (4 | ko) ^ (rr & 7);
  const int srow  = ln >> 3;
  const int sslot = (ln & 7) ^ srow;

  f32x4 acc[4][4];
#pragma unroll
  for (int i = 0; i < 4; i++)
#pragma unroll
    for (int j = 0; j < 4; j++) acc[i][j] = (f32x4)0.f;

  for (int ktc = 0; ktc < K32; ++ktc) {
    __syncthreads();
#pragma unroll
    for (int t = 0; t < 4; ++t) {
      int i = wv * 4 + t;
      const unsigned short* ga =
          A + ((size_t)(m0 + i * 8 + srow) * ldaC + ktc) * 64 + sslot * 8;
      const unsigned short* gb =
          Bt + ((size_t)(n0 + i * 8 + srow) * K32 + ktc) * 64 + sslot * 8;
      __builtin_amdgcn_global_load_lds(
          (const __attribute__((address_space(1))) void*)ga,
          (__attribute__((address_space(3))) void*)((char*)AsV + i * 1024), 16, 0, 0);
      __builtin_amdgcn_global_load_lds(
          (const __attribute__((address_space(1))) void*)gb,
          (__attribute__((address_space(3))) void*)((char*)BsV + i * 1024), 16, 0, 0);
    }
    __syncthreads();

    s16x8 ah[4], al[4], bh[4], bl[4];
#pragma unroll
    for (int mi = 0; mi < 4; ++mi) {
      int r = wr * 64 + mi * 16 + rr;
      ah[mi] = AsV[r * 8 + sh];
      al[mi] = AsV[r * 8 + sl];
    }
#pragma unroll
    for (int ni = 0; ni < 4; ++ni) {
      int c = wc * 64 + ni * 16 + rr;
      bh[ni] = BsV[c * 8 + sh];
      bl[ni] = BsV[c * 8 + sl];
    }
#pragma unroll
    for (int mi = 0; mi < 4; ++mi)
#pragma unroll
      for (int ni = 0; ni < 4; ++ni) {
        acc[mi][ni] = __builtin_amdgcn_mfma_f32_16x16x32_bf16(ah[mi], bh[ni], acc[mi][ni], 0, 0, 0);
        acc[mi][ni] = __builtin_amdgcn_mfma_f32_16x16x32_bf16(ah[mi], bl[ni], acc[mi][ni], 0, 0, 0);
        acc[mi][ni] = __builtin_amdgcn_mfma_f32_16x16x32_bf16(al[mi], bh[ni], acc[mi][ni], 0, 0, 0);
      }
  }

  const int orow = (ln >> 4) * 4;
#pragma unroll
  for (int mi = 0; mi < 4; ++mi)
#pragma unroll
    for (int ni = 0; ni < 4; ++ni) {
      int rowg = m0 + wr * 64 + mi * 16 + orow;
      int colg = n0 + wc * 64 + ni * 16 + rr;
      float bcol = (EPI == 1) ? bias[colg] : 0.f;
#pragma unroll
      for (int i = 0; i < 4; ++i) {
        float v = acc[mi][ni][i];
        if (EPI == 1) v = softplusf(v + bcol);
        C[(size_t)(rowg + i) * ldc + colg] = v;
      }
    }
}

// ---------------------------------------------------------------------------
// xdbl split-K MFMA (round-6 single-buffered): P[kz][4096][96] partials.
// ---------------------------------------------------------------------------
__global__ __launch_bounds__(256, 2) void xdbl_mfma_k(
    const unsigned short* __restrict__ A, const unsigned short* __restrict__ Bt,
    float* __restrict__ P)
{
  __shared__ s16x8 AsV[128 * 8];
  __shared__ s16x8 BsV[128 * 8];

  const int tid = threadIdx.x;
  const int wv  = tid >> 6;
  const int ln  = tid & 63;
  const int wr  = wv >> 1, wc = wv & 1;
  const int kz  = blockIdx.x;            // 0..7
  const int m0  = blockIdx.y * 128;
  const int K32 = 64;                    // K=2048

  const int rr = ln & 15;
  const int ko = ln >> 4;
  const int sh = ko ^ (rr & 7);
  const int sl = (4 | ko) ^ (rr & 7);
  const int srow  = ln >> 3;
  const int sslot = (ln & 7) ^ srow;

  f32x4 acc[4][4];
#pragma unroll
  for (int i = 0; i < 4; i++)
#pragma unroll
    for (int j = 0; j < 4; j++) acc[i][j] = (f32x4)0.f;

  for (int ktc = kz * 8; ktc < kz * 8 + 8; ++ktc) {
    __syncthreads();
#pragma unroll
    for (int t = 0; t < 4; ++t) {
      int i = wv * 4 + t;
      const unsigned short* ga =
          A + ((size_t)(m0 + i * 8 + srow) * K32 + ktc) * 64 + sslot * 8;
      const unsigned short* gb =
          Bt + ((size_t)(i * 8 + srow) * K32 + ktc) * 64 + sslot * 8;
      __builtin_amdgcn_global_load_lds(
          (const __attribute__((address_space(1))) void*)ga,
          (__attribute__((address_space(3))) void*)((char*)AsV + i * 1024), 16, 0, 0);
      __builtin_amdgcn_global_load_lds(
          (const __attribute__((address_space(1))) void*)gb,
          (__attribute__((address_space(3))) void*)((char*)BsV + i * 1024), 16, 0, 0);
    }
    __syncthreads();

    s16x8 ah[4], al[4], bh[4], bl[4];
#pragma unroll
    for (int mi = 0; mi < 4; ++mi) {
      int r = wr * 64 + mi * 16 + rr;
      ah[mi] = AsV[r * 8 + sh];
      al[mi] = AsV[r * 8 + sl];
    }
#pragma unroll
    for (int ni = 0; ni < 4; ++ni) {
      int c = wc * 64 + ni * 16 + rr;
      bh[ni] = BsV[c * 8 + sh];
      bl[ni] = BsV[c * 8 + sl];
    }
#pragma unroll
    for (int mi = 0; mi < 4; ++mi)
#pragma unroll
      for (int ni = 0; ni < 4; ++ni) {
        acc[mi][ni] = __builtin_amdgcn_mfma_f32_16x16x32_bf16(ah[mi], bh[ni], acc[mi][ni], 0, 0, 0);
        acc[mi][ni] = __builtin_amdgcn_mfma_f32_16x16x32_bf16(ah[mi], bl[ni], acc[mi][ni], 0, 0, 0);
        acc[mi][ni] = __builtin_amdgcn_mfma_f32_16x16x32_bf16(al[mi], bh[ni], acc[mi][ni], 0, 0, 0);
      }
  }

  const int orow = (ln >> 4) * 4;
#pragma unroll
  for (int mi = 0; mi < 4; ++mi)
#pragma unroll
    for (int ni = 0; ni < 4; ++ni) {
      int rowg = m0 + wr * 64 + mi * 16 + orow;
      int colg = wc * 64 + ni * 16 + rr;
      if (colg < 96) {
#pragma unroll
        for (int i = 0; i < 4; ++i)
          P[((size_t)kz * 4096 + rowg + i) * 96 + colg] = acc[mi][ni][i];
      }
    }
}

// ---------------------------------------------------------------------------
// fused: xdbl = sum of 8 partials; cols 0..63 -> packed xdblP (dt-GEMM A),
// cols 64..95 -> fp32 xdbl (scan B/C).  Reads Ppart, writes disjoint tail.
// ---------------------------------------------------------------------------
__global__ __launch_bounds__(256) void xdbl_fuse_k(
    const float* __restrict__ P, float* __restrict__ xdbl,
    unsigned short* __restrict__ xdblPs)
{
  int i = blockIdx.x * 256 + threadIdx.x;   // 0..393215
  float s = 0.f;
#pragma unroll
  for (int kz = 0; kz < 8; ++kz) s += P[(size_t)kz * 393216 + i];
  int row = i / 96;
  int col = i - row * 96;
  if (col < 64) {
    unsigned short hv, lv;
    split_one(s, hv, lv);
    size_t cb = ((size_t)row * 2 + (col >> 5)) * 64 + (col & 31);
    xdblPs[cb] = hv;
    xdblPs[cb + 32] = lv;
  } else {
    xdbl[i] = s;
  }
}

// ---------------------------------------------------------------------------
// depthwise causal conv1d (taps=4) + bias + silu, emits fp32 xi AND packed
// xiP (chunk = row*64 + d/32; u16 idx d%32 hi, +32 lo).  Same per-(row,d)
// thread structure as the verified conv_silu_k.
// ---------------------------------------------------------------------------
__global__ __launch_bounds__(256) void conv_silu_pack_k(
    const float* __restrict__ xz, const float* __restrict__ cw,
    const float* __restrict__ cb, float* __restrict__ xi,
    unsigned short* __restrict__ xiPs)
{
  int idx = blockIdx.x * 256 + threadIdx.x;
  int d = idx & (D_INNER - 1);
  int row = idx >> 11;
  int l = row & (SEQLEN - 1);
  float4 w = *(const float4*)(cw + d * 4);
  const float wv[4] = {w.x, w.y, w.z, w.w};
  float acc = cb[d];
#pragma unroll
  for (int j = 0; j < 4; j++) {
    int ll = l - 3 + j;
    if (ll >= 0)
      acc = fmaf(wv[j], xz[(size_t)(row - 3 + j) * 4096 + d], acc);
  }
  float v = siluf(acc);
  xi[idx] = v;
  unsigned short hv, lv;
  split_one(v, hv, lv);
  size_t cbase = ((size_t)row * 64 + (d >> 5)) * 64 + (d & 31);
  xiPs[cbase] = hv;
  xiPs[cbase + 32] = lv;
}

// ---------------------------------------------------------------------------
// chunked selective scan (3 passes); A2 folded in (a2 = -exp(A_log)).
// ---------------------------------------------------------------------------
__global__ __launch_bounds__(256) void scan_pass1(
    const float* __restrict__ dt, const float* __restrict__ xi,
    const float* __restrict__ xdbl, const float* __restrict__ A_log,
    float* __restrict__ cP, float* __restrict__ cH)
{
  int d = blockIdx.x * 256 + threadIdx.x;
  int c = blockIdx.y;
  int b = blockIdx.z;
  float a2[D_STATE], h[D_STATE], P[D_STATE];
#pragma unroll
  for (int n = 0; n < D_STATE; n++) {
    a2[n] = -__expf(A_log[d * D_STATE + n]);
    h[n] = 0.f;
    P[n] = 1.f;
  }
  int rowbase = b * SEQLEN + c * CHUNKLEN;
  for (int l = 0; l < CHUNKLEN; l++) {
    int row = rowbase + l;
    float dtv = dt[(size_t)row * D_INNER + d];
    float xv = xi[(size_t)row * D_INNER + d];
    float dtx = dtv * xv;
    const float* Bp = xdbl + (size_t)row * 96 + 64;
#pragma unroll
    for (int n = 0; n < D_STATE; n++) {
      float dA = __expf(dtv * a2[n]);
      P[n] *= dA;
      h[n] = fmaf(dA, h[n], dtx * Bp[n]);
    }
  }
  size_t base = ((size_t)(b * D_INNER + d) * NCHUNK + c) * D_STATE;
#pragma unroll
  for (int n = 0; n < D_STATE; n++) {
    cP[base + n] = P[n];
    cH[base + n] = h[n];
  }
}

__global__ __launch_bounds__(256) void scan_pass2(
    const float* __restrict__ cP, float* __restrict__ cH)
{
  int t = blockIdx.x * 256 + threadIdx.x;
  size_t base = (size_t)(t >> 4) * (NCHUNK * D_STATE) + (t & 15);
  float h = 0.f;
  for (int c = 0; c < NCHUNK; c++) {
    size_t idx = base + (size_t)c * D_STATE;
    float Pv = cP[idx];
    float q = cH[idx];
    cH[idx] = h;
    h = fmaf(Pv, h, q);
  }
}

// pass3: y = h.C + D*x, gate with silu(z), write PACKED yg into xz's dead
// xi_raw half (row stride 16 KB = 128 chunks).  Reads z from the live half;
// read/write byte ranges are disjoint per row -> race-free.
__global__ __launch_bounds__(256) void scan_pass3(
    const float* __restrict__ dt, const float* __restrict__ xi,
    const float* __restrict__ xdbl, const float* __restrict__ A_log,
    const float* __restrict__ cH, const float* __restrict__ Dvec,
    float* __restrict__ xz)
{
  int d = blockIdx.x * 256 + threadIdx.x;
  int c = blockIdx.y;
  int b = blockIdx.z;
  float a2[D_STATE], h[D_STATE];
  size_t base = ((size_t)(b * D_INNER + d) * NCHUNK + c) * D_STATE;
#pragma unroll
  for (int n = 0; n < D_STATE; n++) {
    a2[n] = -__expf(A_log[d * D_STATE + n]);
    h[n] = cH[base + n];
  }
  float Dd = Dvec[d];
  unsigned short* ygPs = (unsigned short*)xz;
  int rowbase = b * SEQLEN + c * CHUNKLEN;
  for (int l = 0; l < CHUNKLEN; l++) {
    int row = rowbase + l;
    float dtv = dt[(size_t)row * D_INNER + d];
    float xv = xi[(size_t)row * D_INNER + d];
    float dtx = dtv * xv;
    const float* Bp = xdbl + (size_t)row * 96 + 64;
    const float* Cp = Bp + D_STATE;
    float y = Dd * xv;
#pragma unroll
    for (int n = 0; n < D_STATE; n++) {
      float dA = __expf(dtv * a2[n]);
      h[n] = fmaf(dA, h[n], dtx * Bp[n]);
      y = fmaf(h[n], Cp[n], y);
    }
    float z = xz[(size_t)row * 4096 + D_INNER + d];
    float g = y * siluf(z);
    unsigned short hv, lv;
    split_one(g, hv, lv);
    size_t cb = (size_t)row * 8192 + (size_t)(d >> 5) * 64 + (d & 31);
    ygPs[cb] = hv;
    ygPs[cb + 32] = lv;
  }
}

// ---------------------------------------------------------------------------
extern "C" void kernel_launch(void* const* d_in, const int* in_sizes, int n_in,
                              void* d_out, int out_size, void* d_ws,
                              size_t ws_size, hipStream_t stream)
{
  const float* x     = (const float*)d_in[0];
  const float* W_in  = (const float*)d_in[1];
  const float* cw    = (const float*)d_in[2];
  const float* cb    = (const float*)d_in[3];
  const float* W_x   = (const float*)d_in[4];
  const float* W_dt  = (const float*)d_in[5];
  const float* b_dt  = (const float*)d_in[6];
  const float* A_log = (const float*)d_in[7];
  const float* Dv    = (const float*)d_in[8];
  const float* W_out = (const float*)d_in[9];
  float* out = (float*)d_out;

  float* ws    = (float*)d_ws;
  float* xz    = ws;                       // 16,777,216
  float* xi    = xz + 16777216;            //  8,388,608
  float* xdbl  = xi + 8388608;             //    393,216
  float* dtyg  = xdbl + 393216;            //  8,388,608
  float* A2    = dtyg + 8388608;           //     32,768 (unused anchor)
  float* cP    = A2 + 32768;               //  2,097,152
  float* cH    = cP + 2097152;             //  2,097,152
  (void)A2;

  // packed hi/lo bf16 + partial overlays
  unsigned* WinTP  = (unsigned*)dtyg;                  // GEMM1 B (dead after)
  unsigned* xP     = (unsigned*)(dtyg + 4194304);      // GEMM1 A (dead after)
  unsigned* xiP    = (unsigned*)dtyg;                  // xdbl-GEMM A (dead after)
  unsigned* WxTP   = (unsigned*)xdbl;                  // xdbl-GEMM B (dead before fuse)
  float*    Ppart  = cP;                               // [8][4096][96] = 12.6MB of cP+cH
  unsigned short* xdblPs = (unsigned short*)(cP + 3145728);  // 1 MB tail (disjoint from Ppart)
  unsigned* WdtTP  = (unsigned*)(cP + 3145728 + 262144);     // 0.5 MB tail
  unsigned short* ygPs   = (unsigned short*)xz;        // GEMM2 A, stride 128 chunks/row
  unsigned* WoutTP = (unsigned*)cP;                    // GEMM2 B (cP dead post-pass2)

  // W_in (1024x4096) -> transposed+packed WinTP; x -> packed xP
  transpack_k<<<dim3(16, 32), 256, 0, stream>>>(W_in, WinTP, 1024, 4096);
  packsplit_k<<<512, 256, 0, stream>>>(x, xP);

  // xz = x @ W_in   (4096x4096, K=1024)
  mgemm_split<0><<<dim3(32, 32), 256, 0, stream>>>(
      (const unsigned short*)xP, (const unsigned short*)WinTP, nullptr, xz,
      4096, 4096, 1024, 32, 4096);

  // conv + silu -> xi fp32 + packed xiP (packsplit(xi) deleted)
  conv_silu_pack_k<<<32768, 256, 0, stream>>>(xz, cw, cb, xi, (unsigned short*)xiP);

  // x_dbl = xi @ W_x  (split-K=8 MFMA partials, then fused reduce+pack)
  transpack_wx_k<<<64, 128, 0, stream>>>(W_x, WxTP);
  xdbl_mfma_k<<<dim3(8, 32), 256, 0, stream>>>(
      (const unsigned short*)xiP, (const unsigned short*)WxTP, Ppart);
  xdbl_fuse_k<<<1536, 256, 0, stream>>>(Ppart, xdbl, xdblPs);

  // dt = softplus(x_dbl[:, :64] @ W_dt + b_dt) via packed split-bf16 MFMA
  transpack_k<<<dim3(8, 2), 256, 0, stream>>>(W_dt, WdtTP, 64, 2048);
  mgemm_split<1><<<dim3(16, 32), 256, 0, stream>>>(
      xdblPs, (const unsigned short*)WdtTP, b_dt, dtyg,
      4096, 2048, 64, 2, 2048);

  // chunked selective scan; pass3 writes packed yg into xz's dead half
  scan_pass1<<<dim3(8, NCHUNK, NBATCH), 256, 0, stream>>>(dtyg, xi, xdbl, A_log, cP, cH);
  scan_pass2<<<256, 256, 0, stream>>>(cP, cH);
  scan_pass3<<<dim3(8, NCHUNK, NBATCH), 256, 0, stream>>>(dtyg, xi, xdbl, A_log, cH, Dv, xz);

  // W_out -> transposed+packed (cP dead after pass2)
  transpack_k<<<dim3(4, 64), 256, 0, stream>>>(W_out, WoutTP, 2048, 1024);

  // out = yg @ W_out  (4096x1024, K=2048), A row stride = 128 chunks (16 KB)
  mgemm_split<0><<<dim3(8, 32), 256, 0, stream>>>(
      ygPs, (const unsigned short*)WoutTP, nullptr, out,
      4096, 1024, 2048, 128, 1024);
}